// Round 5
// baseline (392.552 us; speedup 1.0000x reference)
//
#include <hip/hip_runtime.h>

typedef __bf16 bf16x8 __attribute__((ext_vector_type(8)));
typedef __bf16 bf16x4 __attribute__((ext_vector_type(4)));
typedef float  f32x4  __attribute__((ext_vector_type(4)));

#define NTOK 256
#define DIM  128

// LDS layout (80 KiB; 2 blocks/CU = 163840 B = exactly the 160 KiB pool):
//  QS [256 tok][32 d] bf16, row 64B, swizzle: 16B-slot ^= ((t>>1)&3)<<4   : 16384
//  KS same as QS                                                          : 16384
//  VT [32 d][256 tok] bf16, row 512B, swizzle: byte ^= ((d&7)<<4)         : 16384
//  PB 16 waves x 2 x 1KiB (P staging, double-buffered per k-chunk)        : 32768
#define QS_OFF 0
#define KS_OFF 16384
#define VT_OFF 32768
#define PB_OFF 49152
#define SMEM_BYTES 81920

#define LOG2E 1.4426950408889634f

// ---------------- prep kernel (tiny, run once per launch) ----------------
// g in [0,65536):        biasT fragment table (pre-scaled by log2e)
// g in [65536,131072):   qkvT / projT bf16 transposed weights
//
// biasT_frag[((h*16+kt)*16+qt)*64+lane][j] =
//     log2e * bias[h][q=qt*16+(lane&15)][k=kt*16+(lane>>4)*4+j]
__global__ void prep_kernel(const float* __restrict__ bias_table,
                            const float* __restrict__ qkv_w,
                            const float* __restrict__ proj_w,
                            float* __restrict__ biasT,
                            __bf16* __restrict__ qkvT,
                            __bf16* __restrict__ projT)
{
    const int g = blockIdx.x * 256 + threadIdx.x;       // 0..131071
    if (g < 65536) {
        const int lane = g & 63;
        const int tile = g >> 6;                        // ((h*16+kt)*16+qt)
        const int qt = tile & 15, kt = (tile >> 4) & 15, h = tile >> 8;
        const int lr = lane & 15, rg = lane >> 4;
        // idx(q,k) = (rq-rk+15)*31 + (cq-ck+15);  rq=qt, cq=lr, rk=kt, ck=rg*4+j
        const int base = (qt - kt + 15) * 31 + (lr - rg * 4 + 15);
        float4 v;
        v.x = bias_table[(base - 0) * 4 + h] * LOG2E;
        v.y = bias_table[(base - 1) * 4 + h] * LOG2E;
        v.z = bias_table[(base - 2) * 4 + h] * LOG2E;
        v.w = bias_table[(base - 3) * 4 + h] * LOG2E;
        *reinterpret_cast<float4*>(biasT + (size_t)g * 4) = v;
    } else {
        const int g1 = g - 65536;
        if (g1 < 49152) {
            const int k = g1 / 384, colg = g1 - k * 384;
            qkvT[colg * 128 + k] = (__bf16)qkv_w[g1];
        } else {
            const int g2 = g1 - 49152;
            const int k = g2 >> 7, col = g2 & 127;
            projT[col * 128 + k] = (__bf16)proj_w[g2];
        }
    }
}

// ---------------- attention kernel (QKV + attn, O^T -> O_ws bf16) ----------------
// 1024 threads = 16 waves, each owning 16 token rows. Halves per-wave register
// state vs the 8-wave version (Xf 32->16 VGPR) so total regs target the <=64
// cliff -> up to 8 waves/SIMD with the 80K LDS allowing 2 blocks/CU.
// All MFMA tiles computed TRANSPOSED (swap A/B) so C-frag's 4 values are 4
// consecutive columns -> packed 8B LDS writes / 8B global stores.

__global__ __launch_bounds__(1024, 4) void attn_main(
    const float* __restrict__ x, const float* __restrict__ noise,
    const float* __restrict__ nstr, const float* __restrict__ biasT,
    const __bf16* __restrict__ qkvT, __bf16* __restrict__ O_ws)
{
    extern __shared__ char smem[];
    const int b = blockIdx.x, tid = threadIdx.x;
    const int wave = tid >> 6, lane = tid & 63;
    const int lr = lane & 15, hi = lane >> 4;
    const int wrow = wave * 16;                 // this wave's 16 token rows
    const int t = wrow + lr;                    // the token this lane's column holds

    const float ns    = nstr[0];
    const float scale = 0.17677669529663689f * LOG2E;   // 32^-0.5 * log2e, folded into Q

    // X fragments in regs (noise added, bf16): B-operand, col=token=lr, k=hi*8+e
    bf16x8 Xf[4];
    {
        const float nz = noise[(size_t)b * NTOK + t] * ns;
        const float* prow = x + ((size_t)b * NTOK + t) * DIM;
#pragma unroll
        for (int kc = 0; kc < 4; ++kc) {
            const float4 a0 = *reinterpret_cast<const float4*>(prow + kc * 32 + hi * 8);
            const float4 a1 = *reinterpret_cast<const float4*>(prow + kc * 32 + hi * 8 + 4);
            bf16x8 v;
            v[0] = (__bf16)(a0.x + nz); v[1] = (__bf16)(a0.y + nz);
            v[2] = (__bf16)(a0.z + nz); v[3] = (__bf16)(a0.w + nz);
            v[4] = (__bf16)(a1.x + nz); v[5] = (__bf16)(a1.y + nz);
            v[6] = (__bf16)(a1.z + nz); v[7] = (__bf16)(a1.w + nz);
            Xf[kc] = v;
        }
    }

    const int tsw = ((t >> 1) & 3) << 4;        // Q/K row swizzle for this lane's token

#pragma unroll 1
    for (int h = 0; h < 4; ++h) {
        __syncthreads();   // QS/KS/VT rewrite vs previous head's readers
        // ---- QKV GEMM (transposed): D[col][token] = mfma(W^T-frag, X-frag) ----
#pragma unroll
        for (int ct = 0; ct < 6; ++ct) {
            const int sec = ct >> 1;
            const int colg = sec * 128 + h * 32 + (ct & 1) * 16 + lr;
            const __bf16* wp = qkvT + colg * 128;
            f32x4 c = (f32x4){0.f, 0.f, 0.f, 0.f};
#pragma unroll
            for (int kc = 0; kc < 4; ++kc) {
                const bf16x8 wf = *reinterpret_cast<const bf16x8*>(wp + kc * 32 + hi * 8);
                c = __builtin_amdgcn_mfma_f32_16x16x32_bf16(wf, Xf[kc], c, 0, 0, 0);
            }
            // c[j] = value for (dloc = (ct&1)*16 + hi*4 + j, token t)
            if (sec == 0) {
                bf16x4 pk;
#pragma unroll
                for (int j = 0; j < 4; ++j) pk[j] = (__bf16)(c[j] * scale);
                *reinterpret_cast<bf16x4*>(smem + QS_OFF + t * 64 +
                    (((ct & 1) * 32 + hi * 8) ^ tsw)) = pk;
            } else if (sec == 1) {
                bf16x4 pk;
#pragma unroll
                for (int j = 0; j < 4; ++j) pk[j] = (__bf16)c[j];
                *reinterpret_cast<bf16x4*>(smem + KS_OFF + t * 64 +
                    (((ct & 1) * 32 + hi * 8) ^ tsw)) = pk;
            } else {
#pragma unroll
                for (int j = 0; j < 4; ++j) {
                    const int d = (ct & 1) * 16 + hi * 4 + j;
                    *reinterpret_cast<__bf16*>(smem + VT_OFF + d * 512 +
                        ((t * 2) ^ ((d & 7) << 4))) = (__bf16)c[j];
                }
            }
        }
        __syncthreads();

        // ---- attention, fused S->exp2->PV per 32-token k-chunk ----
        {
            const bf16x8 qf = *reinterpret_cast<const bf16x8*>(
                smem + QS_OFF + t * 64 + ((hi * 16) ^ tsw));
            char* pb = smem + PB_OFF + wave * 2048;     // 2x1KiB double buffer
            const int psw = ((lr >> 1) & 3) << 4;
            const float* bT = biasT + ((size_t)((h * 16) * 16 + wave) * 64 + lane) * 4;

            float lsum = 0.f;
            f32x4 O0 = (f32x4){0.f, 0.f, 0.f, 0.f};
            f32x4 O1 = (f32x4){0.f, 0.f, 0.f, 0.f};
#pragma unroll 2
            for (int kcc = 0; kcc < 8; ++kcc) {
                char* pbc = pb + ((kcc & 1) << 10);
#pragma unroll
                for (int tt = 0; tt < 2; ++tt) {
                    const int ct = kcc * 2 + tt;
                    const int tk = ct * 16 + lr;
                    const bf16x8 kf = *reinterpret_cast<const bf16x8*>(
                        smem + KS_OFF + tk * 64 + ((hi * 16) ^ (((tk >> 1) & 3) << 4)));
                    f32x4 s = __builtin_amdgcn_mfma_f32_16x16x32_bf16(
                        kf, qf, (f32x4){0.f, 0.f, 0.f, 0.f}, 0, 0, 0);
                    // s[j] = log2e * S[k = ct*16+hi*4+j][q = wave*16+lr] (scale folded)
                    const float4 bv = *reinterpret_cast<const float4*>(bT + ct * 4096);
                    s[0] += bv.x; s[1] += bv.y; s[2] += bv.z; s[3] += bv.w;
                    bf16x4 pk;
#pragma unroll
                    for (int j = 0; j < 4; ++j) {
                        const float p = exp2f(s[j]);    // |S|<<1: no max-subtract needed
                        lsum += p;
                        pk[j] = (__bf16)p;
                    }
                    *reinterpret_cast<bf16x4*>(pbc + lr * 64 + ((tt * 32 + hi * 8) ^ psw)) = pk;
                }
                const bf16x8 pf = *reinterpret_cast<const bf16x8*>(
                    pbc + lr * 64 + ((hi * 16) ^ psw));
                const bf16x8 v0 = *reinterpret_cast<const bf16x8*>(
                    smem + VT_OFF + lr * 512 + ((kcc * 64 + hi * 16) ^ ((lr & 7) << 4)));
                const bf16x8 v1 = *reinterpret_cast<const bf16x8*>(
                    smem + VT_OFF + (16 + lr) * 512 + ((kcc * 64 + hi * 16) ^ ((lr & 7) << 4)));
                O0 = __builtin_amdgcn_mfma_f32_16x16x32_bf16(v0, pf, O0, 0, 0, 0);
                O1 = __builtin_amdgcn_mfma_f32_16x16x32_bf16(v1, pf, O1, 0, 0, 0);
            }
            lsum += __shfl_xor(lsum, 16, 64);
            lsum += __shfl_xor(lsum, 32, 64);
            const float rl = 1.f / lsum;

            bf16x4 oa, ob;
#pragma unroll
            for (int j = 0; j < 4; ++j) {
                oa[j] = (__bf16)(O0[j] * rl);
                ob[j] = (__bf16)(O1[j] * rl);
            }
            const size_t rp = ((size_t)b * NTOK + t) * DIM + h * 32;
            *reinterpret_cast<bf16x4*>(O_ws + rp + hi * 4)      = oa;
            *reinterpret_cast<bf16x4*>(O_ws + rp + 16 + hi * 4) = ob;
        }
    }
}

// ---------------- proj GEMM kernel: out = O @ Wp + b ----------------
__global__ __launch_bounds__(256) void proj_kernel(
    const __bf16* __restrict__ O_ws, const __bf16* __restrict__ projT,
    const float* __restrict__ proj_b, float* __restrict__ out)
{
    const int tid = threadIdx.x;
    const int wave = tid >> 6, lane = tid & 63;
    const int lr = lane & 15, hi = lane >> 4;
    const int row0 = blockIdx.x * 128 + wave * 32;

#pragma unroll
    for (int rb = 0; rb < 2; ++rb) {
        const size_t t = (size_t)row0 + rb * 16 + lr;
        bf16x8 af[4];
#pragma unroll
        for (int kc = 0; kc < 4; ++kc)
            af[kc] = *reinterpret_cast<const bf16x8*>(O_ws + t * DIM + kc * 32 + hi * 8);
#pragma unroll
        for (int ct = 0; ct < 8; ++ct) {
            f32x4 a = (f32x4){0.f, 0.f, 0.f, 0.f};
#pragma unroll
            for (int kc = 0; kc < 4; ++kc) {
                const bf16x8 wpf = *reinterpret_cast<const bf16x8*>(
                    projT + (ct * 16 + lr) * 128 + kc * 32 + hi * 8);
                a = __builtin_amdgcn_mfma_f32_16x16x32_bf16(wpf, af[kc], a, 0, 0, 0);
            }
            const float4 pbv = *reinterpret_cast<const float4*>(proj_b + ct * 16 + hi * 4);
            f32x4 st;
            st[0] = a[0] + pbv.x; st[1] = a[1] + pbv.y;
            st[2] = a[2] + pbv.z; st[3] = a[3] + pbv.w;
            *reinterpret_cast<f32x4*>(out + t * DIM + ct * 16 + hi * 4) = st;
        }
    }
}

// ---------------- launcher ----------------

extern "C" void kernel_launch(void* const* d_in, const int* in_sizes, int n_in,
                              void* d_out, int out_size, void* d_ws, size_t ws_size,
                              hipStream_t stream)
{
    const float* x          = (const float*)d_in[0];
    const float* noise      = (const float*)d_in[1];
    const float* qkv_w      = (const float*)d_in[2];
    const float* proj_w     = (const float*)d_in[3];
    const float* proj_b     = (const float*)d_in[4];
    const float* bias_table = (const float*)d_in[5];
    const float* nstr       = (const float*)d_in[6];
    float* out = (float*)d_out;
    (void)in_sizes; (void)n_in; (void)out_size; (void)ws_size;

    char* ws = (char*)d_ws;
    const size_t OFF_BIAS  = 0;                                   // 1 MiB
    const size_t OFF_QKVT  = (size_t)1 << 20;                     // 96 KiB
    const size_t OFF_PROJT = OFF_QKVT + 384 * 128 * 2;            // 32 KiB
    const size_t OFF_O     = (size_t)2 << 20;                     // 64 MiB

    float*  biasT = (float*)(ws + OFF_BIAS);
    __bf16* qkvT  = (__bf16*)(ws + OFF_QKVT);
    __bf16* projT = (__bf16*)(ws + OFF_PROJT);
    __bf16* O_ws  = (__bf16*)(ws + OFF_O);

    prep_kernel<<<512, 256, 0, stream>>>(bias_table, qkv_w, proj_w, biasT, qkvT, projT);

    hipFuncSetAttribute(reinterpret_cast<const void*>(attn_main),
                        hipFuncAttributeMaxDynamicSharedMemorySize, SMEM_BYTES);
    attn_main<<<1024, 1024, SMEM_BYTES, stream>>>(x, noise, nstr, biasT, qkvT, O_ws);
    proj_kernel<<<2048, 256, 0, stream>>>(O_ws, projT, proj_b, out);
}

// Round 6
// 300.576 us; speedup vs baseline: 1.3060x; 1.3060x over previous
//
#include <hip/hip_runtime.h>

typedef __bf16 bf16x8 __attribute__((ext_vector_type(8)));
typedef __bf16 bf16x4 __attribute__((ext_vector_type(4)));
typedef float  f32x4  __attribute__((ext_vector_type(4)));

#define NTOK 256
#define DIM  128

// LDS layout (64 KiB -> 2 blocks/CU):
//  QS [256 tok][32 d] bf16, row 64B, swizzle: 16B-slot ^= ((t>>1)&3)<<4   : 16384
//  KS same as QS                                                          : 16384
//  VT [32 d][256 tok] bf16, row 512B, swizzle: byte ^= ((d&7)<<4)         : 16384
//  PB 8 waves x 2 x 1KiB  P staging, DOUBLE-buffered per k-chunk (breaks  : 16384
//     the WAR serialization between consecutive k-chunks)
#define QS_OFF 0
#define KS_OFF 16384
#define VT_OFF 32768
#define PB_OFF 49152
#define SMEM_BYTES 65536

#define LOG2E 1.4426950408889634f

// ---------------- prep kernel (tiny, run once per launch) ----------------
// g in [0,65536):        biasT fragment table (pre-scaled by log2e)
// g in [65536,131072):   qkvT / projT bf16 transposed weights
//
// biasT_frag[((h*16+kt)*16+qt)*64+lane][j] =
//     log2e * bias[h][q=qt*16+(lane&15)][k=kt*16+(lane>>4)*4+j]
__global__ void prep_kernel(const float* __restrict__ bias_table,
                            const float* __restrict__ qkv_w,
                            const float* __restrict__ proj_w,
                            float* __restrict__ biasT,
                            __bf16* __restrict__ qkvT,
                            __bf16* __restrict__ projT)
{
    const int g = blockIdx.x * 256 + threadIdx.x;       // 0..131071
    if (g < 65536) {
        const int lane = g & 63;
        const int tile = g >> 6;                        // ((h*16+kt)*16+qt)
        const int qt = tile & 15, kt = (tile >> 4) & 15, h = tile >> 8;
        const int lr = lane & 15, rg = lane >> 4;
        // idx(q,k) = (rq-rk+15)*31 + (cq-ck+15);  rq=qt, cq=lr, rk=kt, ck=rg*4+j
        const int base = (qt - kt + 15) * 31 + (lr - rg * 4 + 15);
        float4 v;
        v.x = bias_table[(base - 0) * 4 + h] * LOG2E;
        v.y = bias_table[(base - 1) * 4 + h] * LOG2E;
        v.z = bias_table[(base - 2) * 4 + h] * LOG2E;
        v.w = bias_table[(base - 3) * 4 + h] * LOG2E;
        *reinterpret_cast<float4*>(biasT + (size_t)g * 4) = v;
    } else {
        const int g1 = g - 65536;
        if (g1 < 49152) {
            const int k = g1 / 384, colg = g1 - k * 384;
            qkvT[colg * 128 + k] = (__bf16)qkv_w[g1];
        } else {
            const int g2 = g1 - 49152;
            const int k = g2 >> 7, col = g2 & 127;
            projT[col * 128 + k] = (__bf16)proj_w[g2];
        }
    }
}

// ---------------- attention kernel (QKV + attn, O^T -> O_ws bf16) ----------------
// 8 waves x 32 token rows (R3 shape — proven best: 2 blocks/CU cover each
// other's barrier drains). All MFMA tiles computed TRANSPOSED (swap A/B) so
// C-frag's 4 values are 4 consecutive columns -> packed 8B LDS writes /
// 8B global stores. launch_bounds (512,4): pin total regs (arch+acc) <= 128
// = the 16-waves/CU tier (R4 showed +4 regs past 128 halves occupancy).

__global__ __launch_bounds__(512, 4) void attn_main(
    const float* __restrict__ x, const float* __restrict__ noise,
    const float* __restrict__ nstr, const float* __restrict__ biasT,
    const __bf16* __restrict__ qkvT, __bf16* __restrict__ O_ws)
{
    extern __shared__ char smem[];
    const int b = blockIdx.x, tid = threadIdx.x;
    const int wave = tid >> 6, lane = tid & 63;
    const int lr = lane & 15, hi = lane >> 4;
    const int wrow = wave * 32;

    const float ns    = nstr[0];
    const float scale = 0.17677669529663689f * LOG2E;   // 32^-0.5 * log2e, folded into Q

    // X fragments in regs (noise added, bf16): B-operand, col=token=lr, k=hi*8+e
    bf16x8 Xf[2][4];
#pragma unroll
    for (int rb = 0; rb < 2; ++rb) {
        const int row = wrow + rb * 16 + lr;
        const float nz = noise[(size_t)b * NTOK + row] * ns;
        const float* prow = x + ((size_t)b * NTOK + row) * DIM;
#pragma unroll
        for (int kc = 0; kc < 4; ++kc) {
            const float4 a0 = *reinterpret_cast<const float4*>(prow + kc * 32 + hi * 8);
            const float4 a1 = *reinterpret_cast<const float4*>(prow + kc * 32 + hi * 8 + 4);
            bf16x8 v;
            v[0] = (__bf16)(a0.x + nz); v[1] = (__bf16)(a0.y + nz);
            v[2] = (__bf16)(a0.z + nz); v[3] = (__bf16)(a0.w + nz);
            v[4] = (__bf16)(a1.x + nz); v[5] = (__bf16)(a1.y + nz);
            v[6] = (__bf16)(a1.z + nz); v[7] = (__bf16)(a1.w + nz);
            Xf[rb][kc] = v;
        }
    }

#pragma unroll 1
    for (int h = 0; h < 4; ++h) {
        __syncthreads();   // QS/KS/VT rewrite vs previous head's readers
        // ---- QKV GEMM (transposed): D[col][token] = mfma(W^T-frag, X-frag) ----
#pragma unroll
        for (int rb = 0; rb < 2; ++rb) {
            const int t = wrow + rb * 16 + lr;          // token in this lane's column
            const int tsw = ((t >> 1) & 3) << 4;
#pragma unroll
            for (int ct = 0; ct < 6; ++ct) {
                const int sec = ct >> 1;
                const int colg = sec * 128 + h * 32 + (ct & 1) * 16 + lr;
                const __bf16* wp = qkvT + colg * 128;
                f32x4 c = (f32x4){0.f, 0.f, 0.f, 0.f};
#pragma unroll
                for (int kc = 0; kc < 4; ++kc) {
                    const bf16x8 wf = *reinterpret_cast<const bf16x8*>(wp + kc * 32 + hi * 8);
                    c = __builtin_amdgcn_mfma_f32_16x16x32_bf16(wf, Xf[rb][kc], c, 0, 0, 0);
                }
                // c[j] = value for (dloc = (ct&1)*16 + hi*4 + j, token t)
                if (sec == 0) {
                    bf16x4 pk;
#pragma unroll
                    for (int j = 0; j < 4; ++j) pk[j] = (__bf16)(c[j] * scale);
                    *reinterpret_cast<bf16x4*>(smem + QS_OFF + t * 64 +
                        (((ct & 1) * 32 + hi * 8) ^ tsw)) = pk;
                } else if (sec == 1) {
                    bf16x4 pk;
#pragma unroll
                    for (int j = 0; j < 4; ++j) pk[j] = (__bf16)c[j];
                    *reinterpret_cast<bf16x4*>(smem + KS_OFF + t * 64 +
                        (((ct & 1) * 32 + hi * 8) ^ tsw)) = pk;
                } else {
#pragma unroll
                    for (int j = 0; j < 4; ++j) {
                        const int d = (ct & 1) * 16 + hi * 4 + j;
                        *reinterpret_cast<__bf16*>(smem + VT_OFF + d * 512 +
                            ((t * 2) ^ ((d & 7) << 4))) = (__bf16)c[j];
                    }
                }
            }
        }
        __syncthreads();

        // ---- attention, fused S->exp2->PV per 32-token k-chunk ----
#pragma unroll
        for (int rb = 0; rb < 2; ++rb) {
            const int rt = wave * 2 + rb;               // q-token tile index
            const int tq = wrow + rb * 16 + lr;
            const bf16x8 qf = *reinterpret_cast<const bf16x8*>(
                smem + QS_OFF + tq * 64 + ((hi * 16) ^ (((tq >> 1) & 3) << 4)));
            char* pb = smem + PB_OFF + wave * 2048;     // 2 x 1KiB double buffer
            const int psw = ((lr >> 1) & 3) << 4;
            const float* bT = biasT + ((size_t)((h * 16) * 16 + rt) * 64 + lane) * 4;

            f32x4 ls = (f32x4){0.f, 0.f, 0.f, 0.f};    // 4 parallel lsum partials
            f32x4 O0 = (f32x4){0.f, 0.f, 0.f, 0.f};
            f32x4 O1 = (f32x4){0.f, 0.f, 0.f, 0.f};
#pragma unroll 2
            for (int kcc = 0; kcc < 8; ++kcc) {
                char* pbc = pb + ((kcc & 1) << 10);     // alternate buffers -> no WAR
#pragma unroll
                for (int tt = 0; tt < 2; ++tt) {
                    const int ct = kcc * 2 + tt;
                    const int tk = ct * 16 + lr;
                    const bf16x8 kf = *reinterpret_cast<const bf16x8*>(
                        smem + KS_OFF + tk * 64 + ((hi * 16) ^ (((tk >> 1) & 3) << 4)));
                    f32x4 s = __builtin_amdgcn_mfma_f32_16x16x32_bf16(
                        kf, qf, (f32x4){0.f, 0.f, 0.f, 0.f}, 0, 0, 0);
                    // s[j] = log2e * S[k = ct*16+hi*4+j][q = rt*16+lr] (scale folded)
                    const float4 bv = *reinterpret_cast<const float4*>(bT + ct * 4096);
                    s[0] += bv.x; s[1] += bv.y; s[2] += bv.z; s[3] += bv.w;
                    bf16x4 pk;
#pragma unroll
                    for (int j = 0; j < 4; ++j) {
                        const float p = exp2f(s[j]);    // |S|<<1: no max-subtract needed
                        ls[j] += p;
                        pk[j] = (__bf16)p;
                    }
                    *reinterpret_cast<bf16x4*>(pbc + lr * 64 + ((tt * 32 + hi * 8) ^ psw)) = pk;
                }
                const bf16x8 pf = *reinterpret_cast<const bf16x8*>(
                    pbc + lr * 64 + ((hi * 16) ^ psw));
                const bf16x8 v0 = *reinterpret_cast<const bf16x8*>(
                    smem + VT_OFF + lr * 512 + ((kcc * 64 + hi * 16) ^ ((lr & 7) << 4)));
                const bf16x8 v1 = *reinterpret_cast<const bf16x8*>(
                    smem + VT_OFF + (16 + lr) * 512 + ((kcc * 64 + hi * 16) ^ ((lr & 7) << 4)));
                O0 = __builtin_amdgcn_mfma_f32_16x16x32_bf16(v0, pf, O0, 0, 0, 0);
                O1 = __builtin_amdgcn_mfma_f32_16x16x32_bf16(v1, pf, O1, 0, 0, 0);
            }
            float lsum = (ls[0] + ls[1]) + (ls[2] + ls[3]);
            lsum += __shfl_xor(lsum, 16, 64);
            lsum += __shfl_xor(lsum, 32, 64);
            const float rl = 1.f / lsum;

            bf16x4 oa, ob;
#pragma unroll
            for (int j = 0; j < 4; ++j) {
                oa[j] = (__bf16)(O0[j] * rl);
                ob[j] = (__bf16)(O1[j] * rl);
            }
            const size_t rp = ((size_t)b * NTOK + tq) * DIM + h * 32;
            *reinterpret_cast<bf16x4*>(O_ws + rp + hi * 4)      = oa;
            *reinterpret_cast<bf16x4*>(O_ws + rp + 16 + hi * 4) = ob;
        }
    }
}

// ---------------- proj GEMM kernel: out = O @ Wp + b ----------------
__global__ __launch_bounds__(256) void proj_kernel(
    const __bf16* __restrict__ O_ws, const __bf16* __restrict__ projT,
    const float* __restrict__ proj_b, float* __restrict__ out)
{
    const int tid = threadIdx.x;
    const int wave = tid >> 6, lane = tid & 63;
    const int lr = lane & 15, hi = lane >> 4;
    const int row0 = blockIdx.x * 128 + wave * 32;

#pragma unroll
    for (int rb = 0; rb < 2; ++rb) {
        const size_t t = (size_t)row0 + rb * 16 + lr;
        bf16x8 af[4];
#pragma unroll
        for (int kc = 0; kc < 4; ++kc)
            af[kc] = *reinterpret_cast<const bf16x8*>(O_ws + t * DIM + kc * 32 + hi * 8);
#pragma unroll
        for (int ct = 0; ct < 8; ++ct) {
            f32x4 a = (f32x4){0.f, 0.f, 0.f, 0.f};
#pragma unroll
            for (int kc = 0; kc < 4; ++kc) {
                const bf16x8 wpf = *reinterpret_cast<const bf16x8*>(
                    projT + (ct * 16 + lr) * 128 + kc * 32 + hi * 8);
                a = __builtin_amdgcn_mfma_f32_16x16x32_bf16(wpf, af[kc], a, 0, 0, 0);
            }
            const float4 pbv = *reinterpret_cast<const float4*>(proj_b + ct * 16 + hi * 4);
            f32x4 st;
            st[0] = a[0] + pbv.x; st[1] = a[1] + pbv.y;
            st[2] = a[2] + pbv.z; st[3] = a[3] + pbv.w;
            *reinterpret_cast<f32x4*>(out + t * DIM + ct * 16 + hi * 4) = st;
        }
    }
}

// ---------------- launcher ----------------

extern "C" void kernel_launch(void* const* d_in, const int* in_sizes, int n_in,
                              void* d_out, int out_size, void* d_ws, size_t ws_size,
                              hipStream_t stream)
{
    const float* x          = (const float*)d_in[0];
    const float* noise      = (const float*)d_in[1];
    const float* qkv_w      = (const float*)d_in[2];
    const float* proj_w     = (const float*)d_in[3];
    const float* proj_b     = (const float*)d_in[4];
    const float* bias_table = (const float*)d_in[5];
    const float* nstr       = (const float*)d_in[6];
    float* out = (float*)d_out;
    (void)in_sizes; (void)n_in; (void)out_size; (void)ws_size;

    char* ws = (char*)d_ws;
    const size_t OFF_BIAS  = 0;                                   // 1 MiB
    const size_t OFF_QKVT  = (size_t)1 << 20;                     // 96 KiB
    const size_t OFF_PROJT = OFF_QKVT + 384 * 128 * 2;            // 32 KiB
    const size_t OFF_O     = (size_t)2 << 20;                     // 64 MiB

    float*  biasT = (float*)(ws + OFF_BIAS);
    __bf16* qkvT  = (__bf16*)(ws + OFF_QKVT);
    __bf16* projT = (__bf16*)(ws + OFF_PROJT);
    __bf16* O_ws  = (__bf16*)(ws + OFF_O);

    prep_kernel<<<512, 256, 0, stream>>>(bias_table, qkv_w, proj_w, biasT, qkvT, projT);

    hipFuncSetAttribute(reinterpret_cast<const void*>(attn_main),
                        hipFuncAttributeMaxDynamicSharedMemorySize, SMEM_BYTES);
    attn_main<<<1024, 512, SMEM_BYTES, stream>>>(x, noise, nstr, biasT, qkvT, O_ws);
    proj_kernel<<<2048, 256, 0, stream>>>(O_ws, projT, proj_b, out);
}

// Round 7
// 257.619 us; speedup vs baseline: 1.5238x; 1.1667x over previous
//
#include <hip/hip_runtime.h>

typedef __bf16 bf16x8 __attribute__((ext_vector_type(8)));
typedef __bf16 bf16x4 __attribute__((ext_vector_type(4)));
typedef float  f32x4  __attribute__((ext_vector_type(4)));

#define NTOK 256
#define DIM  128

// LDS layout (56 KiB -> 2 blocks/CU):  [R3-proven layout]
//  QS [256 tok][32 d] bf16, row 64B, swizzle: 16B-slot ^= ((t>>1)&3)<<4   : 16384
//  KS same as QS                                                          : 16384
//  VT [32 d][256 tok] bf16, row 512B, swizzle: byte ^= ((d&7)<<4)         : 16384
//  PB 8 waves x 1KiB (P staging; per-wave LDS ops are in-order -> safe)   :  8192
#define QS_OFF 0
#define KS_OFF 16384
#define VT_OFF 32768
#define PB_OFF 49152
#define SMEM_BYTES 57344

#define LOG2E 1.4426950408889634f

// ---------------- prep kernel (tiny, run once per launch) ----------------
// g in [0,65536):        biasT fragment table (pre-scaled by log2e)
// g in [65536,131072):   qkvT / projT bf16 transposed weights
//
// biasT_frag[((h*16+kt)*16+qt)*64+lane][j] =
//     log2e * bias[h][q=qt*16+(lane&15)][k=kt*16+(lane>>4)*4+j]
__global__ void prep_kernel(const float* __restrict__ bias_table,
                            const float* __restrict__ qkv_w,
                            const float* __restrict__ proj_w,
                            float* __restrict__ biasT,
                            __bf16* __restrict__ qkvT,
                            __bf16* __restrict__ projT)
{
    const int g = blockIdx.x * 256 + threadIdx.x;       // 0..131071
    if (g < 65536) {
        const int lane = g & 63;
        const int tile = g >> 6;                        // ((h*16+kt)*16+qt)
        const int qt = tile & 15, kt = (tile >> 4) & 15, h = tile >> 8;
        const int lr = lane & 15, rg = lane >> 4;
        // idx(q,k) = (rq-rk+15)*31 + (cq-ck+15);  rq=qt, cq=lr, rk=kt, ck=rg*4+j
        const int base = (qt - kt + 15) * 31 + (lr - rg * 4 + 15);
        float4 v;
        v.x = bias_table[(base - 0) * 4 + h] * LOG2E;
        v.y = bias_table[(base - 1) * 4 + h] * LOG2E;
        v.z = bias_table[(base - 2) * 4 + h] * LOG2E;
        v.w = bias_table[(base - 3) * 4 + h] * LOG2E;
        *reinterpret_cast<float4*>(biasT + (size_t)g * 4) = v;
    } else {
        const int g1 = g - 65536;
        if (g1 < 49152) {
            const int k = g1 / 384, colg = g1 - k * 384;
            qkvT[colg * 128 + k] = (__bf16)qkv_w[g1];
        } else {
            const int g2 = g1 - 49152;
            const int k = g2 >> 7, col = g2 & 127;
            projT[col * 128 + k] = (__bf16)proj_w[g2];
        }
    }
}

// ---------------- attention kernel (QKV + attn, O^T -> O_ws bf16) ----------------
// R3-exact structure: 8 waves x 32 token rows, 2 blocks/CU, single P buffer,
// serial lsum, launch_bounds(512,2) (cap 256; allocator lands at 64 arch —
// keep arch VGPR <= 64: 65+ breaks the 16-waves/CU tier, R4 evidence).
// Only delta vs R3: exp2 via raw v_exp_f32 with log2e pre-folded into
// Q-scale and bias table (removes the per-element mul inside __expf).

__global__ __launch_bounds__(512, 2) void attn_main(
    const float* __restrict__ x, const float* __restrict__ noise,
    const float* __restrict__ nstr, const float* __restrict__ biasT,
    const __bf16* __restrict__ qkvT, __bf16* __restrict__ O_ws)
{
    extern __shared__ char smem[];
    const int b = blockIdx.x, tid = threadIdx.x;
    const int wave = tid >> 6, lane = tid & 63;
    const int lr = lane & 15, hi = lane >> 4;
    const int wrow = wave * 32;

    const float ns    = nstr[0];
    const float scale = 0.17677669529663689f * LOG2E;   // 32^-0.5 * log2e, folded into Q

    // X fragments in regs (noise added, bf16): B-operand, col=token=lr, k=hi*8+e
    bf16x8 Xf[2][4];
#pragma unroll
    for (int rb = 0; rb < 2; ++rb) {
        const int row = wrow + rb * 16 + lr;
        const float nz = noise[(size_t)b * NTOK + row] * ns;
        const float* prow = x + ((size_t)b * NTOK + row) * DIM;
#pragma unroll
        for (int kc = 0; kc < 4; ++kc) {
            const float4 a0 = *reinterpret_cast<const float4*>(prow + kc * 32 + hi * 8);
            const float4 a1 = *reinterpret_cast<const float4*>(prow + kc * 32 + hi * 8 + 4);
            bf16x8 v;
            v[0] = (__bf16)(a0.x + nz); v[1] = (__bf16)(a0.y + nz);
            v[2] = (__bf16)(a0.z + nz); v[3] = (__bf16)(a0.w + nz);
            v[4] = (__bf16)(a1.x + nz); v[5] = (__bf16)(a1.y + nz);
            v[6] = (__bf16)(a1.z + nz); v[7] = (__bf16)(a1.w + nz);
            Xf[rb][kc] = v;
        }
    }

#pragma unroll 1
    for (int h = 0; h < 4; ++h) {
        __syncthreads();   // QS/KS/VT rewrite vs previous head's readers
        // ---- QKV GEMM (transposed): D[col][token] = mfma(W^T-frag, X-frag) ----
#pragma unroll
        for (int rb = 0; rb < 2; ++rb) {
            const int t = wrow + rb * 16 + lr;          // token in this lane's column
            const int tsw = ((t >> 1) & 3) << 4;
#pragma unroll
            for (int ct = 0; ct < 6; ++ct) {
                const int sec = ct >> 1;
                const int colg = sec * 128 + h * 32 + (ct & 1) * 16 + lr;
                const __bf16* wp = qkvT + colg * 128;
                f32x4 c = (f32x4){0.f, 0.f, 0.f, 0.f};
#pragma unroll
                for (int kc = 0; kc < 4; ++kc) {
                    const bf16x8 wf = *reinterpret_cast<const bf16x8*>(wp + kc * 32 + hi * 8);
                    c = __builtin_amdgcn_mfma_f32_16x16x32_bf16(wf, Xf[rb][kc], c, 0, 0, 0);
                }
                // c[j] = value for (dloc = (ct&1)*16 + hi*4 + j, token t)
                if (sec == 0) {
                    bf16x4 pk;
#pragma unroll
                    for (int j = 0; j < 4; ++j) pk[j] = (__bf16)(c[j] * scale);
                    *reinterpret_cast<bf16x4*>(smem + QS_OFF + t * 64 +
                        (((ct & 1) * 32 + hi * 8) ^ tsw)) = pk;
                } else if (sec == 1) {
                    bf16x4 pk;
#pragma unroll
                    for (int j = 0; j < 4; ++j) pk[j] = (__bf16)c[j];
                    *reinterpret_cast<bf16x4*>(smem + KS_OFF + t * 64 +
                        (((ct & 1) * 32 + hi * 8) ^ tsw)) = pk;
                } else {
#pragma unroll
                    for (int j = 0; j < 4; ++j) {
                        const int d = (ct & 1) * 16 + hi * 4 + j;
                        *reinterpret_cast<__bf16*>(smem + VT_OFF + d * 512 +
                            ((t * 2) ^ ((d & 7) << 4))) = (__bf16)c[j];
                    }
                }
            }
        }
        __syncthreads();

        // ---- attention, fused S->exp2->PV per 32-token k-chunk ----
#pragma unroll
        for (int rb = 0; rb < 2; ++rb) {
            const int rt = wave * 2 + rb;               // q-token tile index
            const int tq = wrow + rb * 16 + lr;
            const bf16x8 qf = *reinterpret_cast<const bf16x8*>(
                smem + QS_OFF + tq * 64 + ((hi * 16) ^ (((tq >> 1) & 3) << 4)));
            char* pb = smem + PB_OFF + wave * 1024;
            const int psw = ((lr >> 1) & 3) << 4;
            const float* bT = biasT + ((size_t)((h * 16) * 16 + rt) * 64 + lane) * 4;

            float lsum = 0.f;
            f32x4 O0 = (f32x4){0.f, 0.f, 0.f, 0.f};
            f32x4 O1 = (f32x4){0.f, 0.f, 0.f, 0.f};
#pragma unroll 2
            for (int kcc = 0; kcc < 8; ++kcc) {
#pragma unroll
                for (int tt = 0; tt < 2; ++tt) {
                    const int ct = kcc * 2 + tt;
                    const int tk = ct * 16 + lr;
                    const bf16x8 kf = *reinterpret_cast<const bf16x8*>(
                        smem + KS_OFF + tk * 64 + ((hi * 16) ^ (((tk >> 1) & 3) << 4)));
                    f32x4 s = __builtin_amdgcn_mfma_f32_16x16x32_bf16(
                        kf, qf, (f32x4){0.f, 0.f, 0.f, 0.f}, 0, 0, 0);
                    // s[j] = log2e * S[k = ct*16+hi*4+j][q = rt*16+lr] (scale folded)
                    const float4 bv = *reinterpret_cast<const float4*>(bT + ct * 4096);
                    s[0] += bv.x; s[1] += bv.y; s[2] += bv.z; s[3] += bv.w;
                    bf16x4 pk;
#pragma unroll
                    for (int j = 0; j < 4; ++j) {
                        const float p = __builtin_amdgcn_exp2f(s[j]);  // raw v_exp_f32
                        lsum += p;
                        pk[j] = (__bf16)p;
                    }
                    *reinterpret_cast<bf16x4*>(pb + lr * 64 + ((tt * 32 + hi * 8) ^ psw)) = pk;
                }
                const bf16x8 pf = *reinterpret_cast<const bf16x8*>(
                    pb + lr * 64 + ((hi * 16) ^ psw));
                const bf16x8 v0 = *reinterpret_cast<const bf16x8*>(
                    smem + VT_OFF + lr * 512 + ((kcc * 64 + hi * 16) ^ ((lr & 7) << 4)));
                const bf16x8 v1 = *reinterpret_cast<const bf16x8*>(
                    smem + VT_OFF + (16 + lr) * 512 + ((kcc * 64 + hi * 16) ^ ((lr & 7) << 4)));
                O0 = __builtin_amdgcn_mfma_f32_16x16x32_bf16(v0, pf, O0, 0, 0, 0);
                O1 = __builtin_amdgcn_mfma_f32_16x16x32_bf16(v1, pf, O1, 0, 0, 0);
            }
            lsum += __shfl_xor(lsum, 16, 64);
            lsum += __shfl_xor(lsum, 32, 64);
            const float rl = 1.f / lsum;

            bf16x4 oa, ob;
#pragma unroll
            for (int j = 0; j < 4; ++j) {
                oa[j] = (__bf16)(O0[j] * rl);
                ob[j] = (__bf16)(O1[j] * rl);
            }
            const size_t rp = ((size_t)b * NTOK + tq) * DIM + h * 32;
            *reinterpret_cast<bf16x4*>(O_ws + rp + hi * 4)      = oa;
            *reinterpret_cast<bf16x4*>(O_ws + rp + 16 + hi * 4) = ob;
        }
    }
}

// ---------------- proj GEMM kernel: out = O @ Wp + b ----------------
__global__ __launch_bounds__(256) void proj_kernel(
    const __bf16* __restrict__ O_ws, const __bf16* __restrict__ projT,
    const float* __restrict__ proj_b, float* __restrict__ out)
{
    const int tid = threadIdx.x;
    const int wave = tid >> 6, lane = tid & 63;
    const int lr = lane & 15, hi = lane >> 4;
    const int row0 = blockIdx.x * 128 + wave * 32;

#pragma unroll
    for (int rb = 0; rb < 2; ++rb) {
        const size_t t = (size_t)row0 + rb * 16 + lr;
        bf16x8 af[4];
#pragma unroll
        for (int kc = 0; kc < 4; ++kc)
            af[kc] = *reinterpret_cast<const bf16x8*>(O_ws + t * DIM + kc * 32 + hi * 8);
#pragma unroll
        for (int ct = 0; ct < 8; ++ct) {
            f32x4 a = (f32x4){0.f, 0.f, 0.f, 0.f};
#pragma unroll
            for (int kc = 0; kc < 4; ++kc) {
                const bf16x8 wpf = *reinterpret_cast<const bf16x8*>(
                    projT + (ct * 16 + lr) * 128 + kc * 32 + hi * 8);
                a = __builtin_amdgcn_mfma_f32_16x16x32_bf16(wpf, af[kc], a, 0, 0, 0);
            }
            const float4 pbv = *reinterpret_cast<const float4*>(proj_b + ct * 16 + hi * 4);
            f32x4 st;
            st[0] = a[0] + pbv.x; st[1] = a[1] + pbv.y;
            st[2] = a[2] + pbv.z; st[3] = a[3] + pbv.w;
            *reinterpret_cast<f32x4*>(out + t * DIM + ct * 16 + hi * 4) = st;
        }
    }
}

// ---------------- launcher ----------------

extern "C" void kernel_launch(void* const* d_in, const int* in_sizes, int n_in,
                              void* d_out, int out_size, void* d_ws, size_t ws_size,
                              hipStream_t stream)
{
    const float* x          = (const float*)d_in[0];
    const float* noise      = (const float*)d_in[1];
    const float* qkv_w      = (const float*)d_in[2];
    const float* proj_w     = (const float*)d_in[3];
    const float* proj_b     = (const float*)d_in[4];
    const float* bias_table = (const float*)d_in[5];
    const float* nstr       = (const float*)d_in[6];
    float* out = (float*)d_out;
    (void)in_sizes; (void)n_in; (void)out_size; (void)ws_size;

    char* ws = (char*)d_ws;
    const size_t OFF_BIAS  = 0;                                   // 1 MiB
    const size_t OFF_QKVT  = (size_t)1 << 20;                     // 96 KiB
    const size_t OFF_PROJT = OFF_QKVT + 384 * 128 * 2;            // 32 KiB
    const size_t OFF_O     = (size_t)2 << 20;                     // 64 MiB

    float*  biasT = (float*)(ws + OFF_BIAS);
    __bf16* qkvT  = (__bf16*)(ws + OFF_QKVT);
    __bf16* projT = (__bf16*)(ws + OFF_PROJT);
    __bf16* O_ws  = (__bf16*)(ws + OFF_O);

    prep_kernel<<<512, 256, 0, stream>>>(bias_table, qkv_w, proj_w, biasT, qkvT, projT);

    hipFuncSetAttribute(reinterpret_cast<const void*>(attn_main),
                        hipFuncAttributeMaxDynamicSharedMemorySize, SMEM_BYTES);
    attn_main<<<1024, 512, SMEM_BYTES, stream>>>(x, noise, nstr, biasT, qkvT, O_ws);
    proj_kernel<<<2048, 256, 0, stream>>>(O_ws, projT, proj_b, out);
}

// Round 8
// 257.578 us; speedup vs baseline: 1.5240x; 1.0002x over previous
//
#include <hip/hip_runtime.h>

typedef __bf16 bf16x8 __attribute__((ext_vector_type(8)));
typedef __bf16 bf16x4 __attribute__((ext_vector_type(4)));
typedef float  f32x4  __attribute__((ext_vector_type(4)));

#define NTOK 256
#define DIM  128

// LDS layout (56 KiB -> 2 blocks/CU):  [R3-proven layout]
//  QS [256 tok][32 d] bf16, row 64B, swizzle: 16B-slot ^= ((t>>1)&3)<<4   : 16384
//  KS same as QS                                                          : 16384
//  VT [32 d][256 tok] bf16, row 512B, swizzle: byte ^= ((d&7)<<4)         : 16384
//  PB 8 waves x 1KiB (P staging; per-wave LDS ops are in-order -> safe)   :  8192
#define QS_OFF 0
#define KS_OFF 16384
#define VT_OFF 32768
#define PB_OFF 49152
#define SMEM_BYTES 57344

#define LOG2E 1.4426950408889634f

// ---------------- prep kernel (tiny, run once per launch) ----------------
// g in [0,65536):        biasT fragment table (pre-scaled by log2e)
// g in [65536,131072):   qkvT / projT bf16 transposed weights
//
// biasT_frag[((h*16+kt)*16+qt)*64+lane][j] =
//     log2e * bias[h][q=qt*16+(lane&15)][k=kt*16+(lane>>4)*4+j]
//
// projT k-axis is PERMUTED to match the attn O-store order: within head,
// memory position p = hi*8+e holds d = (e<4) ? hi*4+e : 16+hi*4+(e-4).
__global__ void prep_kernel(const float* __restrict__ bias_table,
                            const float* __restrict__ qkv_w,
                            const float* __restrict__ proj_w,
                            float* __restrict__ biasT,
                            __bf16* __restrict__ qkvT,
                            __bf16* __restrict__ projT)
{
    const int g = blockIdx.x * 256 + threadIdx.x;       // 0..131071
    if (g < 65536) {
        const int lane = g & 63;
        const int tile = g >> 6;                        // ((h*16+kt)*16+qt)
        const int qt = tile & 15, kt = (tile >> 4) & 15, h = tile >> 8;
        const int lr = lane & 15, rg = lane >> 4;
        // idx(q,k) = (rq-rk+15)*31 + (cq-ck+15);  rq=qt, cq=lr, rk=kt, ck=rg*4+j
        const int base = (qt - kt + 15) * 31 + (lr - rg * 4 + 15);
        float4 v;
        v.x = bias_table[(base - 0) * 4 + h] * LOG2E;
        v.y = bias_table[(base - 1) * 4 + h] * LOG2E;
        v.z = bias_table[(base - 2) * 4 + h] * LOG2E;
        v.w = bias_table[(base - 3) * 4 + h] * LOG2E;
        *reinterpret_cast<float4*>(biasT + (size_t)g * 4) = v;
    } else {
        const int g1 = g - 65536;
        if (g1 < 49152) {
            const int k = g1 / 384, colg = g1 - k * 384;
            qkvT[colg * 128 + k] = (__bf16)qkv_w[g1];
        } else {
            const int g2 = g1 - 49152;
            const int k = g2 >> 7, col = g2 & 127;      // k = source proj_w row
            const int h = k >> 5, d = k & 31;
            const int p = ((d & 15) >> 2) * 8 + ((d >> 4) & 1) * 4 + (d & 3);
            projT[col * 128 + h * 32 + p] = (__bf16)proj_w[g2];
        }
    }
}

// ---------------- attention kernel (QKV + attn, O^T -> O_ws bf16) ----------------
// R3-exact structure: 8 waves x 32 token rows, 2 blocks/CU, single P buffer,
// serial lsum, launch_bounds(512,2). Keep arch VGPR <= 64 (65+ breaks the
// 16-waves/CU tier: total arch+acc regs 128 -> 4 waves/SIMD, R4 evidence).
// R8 deltas: bias via MFMA C-operand; V^T via packed stores (non-swapped
// mfma for the V tiles); O as single 16B store (k-permutation in projT).

__global__ __launch_bounds__(512, 2) void attn_main(
    const float* __restrict__ x, const float* __restrict__ noise,
    const float* __restrict__ nstr, const float* __restrict__ biasT,
    const __bf16* __restrict__ qkvT, __bf16* __restrict__ O_ws)
{
    extern __shared__ char smem[];
    const int b = blockIdx.x, tid = threadIdx.x;
    const int wave = tid >> 6, lane = tid & 63;
    const int lr = lane & 15, hi = lane >> 4;
    const int wrow = wave * 32;

    const float ns    = nstr[0];
    const float scale = 0.17677669529663689f * LOG2E;   // 32^-0.5 * log2e, folded into Q

    // X fragments in regs (noise added, bf16). Lane (lr,hi) holds X[token=
    // wrow+rb*16+lr][k=kc*32+hi*8+e] — valid as BOTH A-frag (row=token) and
    // B-frag (col=token): A/B lane-data layouts coincide.
    bf16x8 Xf[2][4];
#pragma unroll
    for (int rb = 0; rb < 2; ++rb) {
        const int row = wrow + rb * 16 + lr;
        const float nz = noise[(size_t)b * NTOK + row] * ns;
        const float* prow = x + ((size_t)b * NTOK + row) * DIM;
#pragma unroll
        for (int kc = 0; kc < 4; ++kc) {
            const float4 a0 = *reinterpret_cast<const float4*>(prow + kc * 32 + hi * 8);
            const float4 a1 = *reinterpret_cast<const float4*>(prow + kc * 32 + hi * 8 + 4);
            bf16x8 v;
            v[0] = (__bf16)(a0.x + nz); v[1] = (__bf16)(a0.y + nz);
            v[2] = (__bf16)(a0.z + nz); v[3] = (__bf16)(a0.w + nz);
            v[4] = (__bf16)(a1.x + nz); v[5] = (__bf16)(a1.y + nz);
            v[6] = (__bf16)(a1.z + nz); v[7] = (__bf16)(a1.w + nz);
            Xf[rb][kc] = v;
        }
    }

#pragma unroll 1
    for (int h = 0; h < 4; ++h) {
        __syncthreads();   // QS/KS/VT rewrite vs previous head's readers
        // ---- QKV GEMM ----
#pragma unroll
        for (int rb = 0; rb < 2; ++rb) {
            const int t = wrow + rb * 16 + lr;          // token in this lane's column
            const int tsw = ((t >> 1) & 3) << 4;
#pragma unroll
            for (int ct = 0; ct < 6; ++ct) {
                const int sec = ct >> 1;
                const int colg = sec * 128 + h * 32 + (ct & 1) * 16 + lr;
                const __bf16* wp = qkvT + colg * 128;
                f32x4 c = (f32x4){0.f, 0.f, 0.f, 0.f};
                if (sec < 2) {
                    // transposed: D[col][token] = mfma(W-frag, X-frag)
#pragma unroll
                    for (int kc = 0; kc < 4; ++kc) {
                        const bf16x8 wf = *reinterpret_cast<const bf16x8*>(wp + kc * 32 + hi * 8);
                        c = __builtin_amdgcn_mfma_f32_16x16x32_bf16(wf, Xf[rb][kc], c, 0, 0, 0);
                    }
                    // c[j] = (dloc = (ct&1)*16 + hi*4 + j, token t)
                    if (sec == 0) {
                        bf16x4 pk;
#pragma unroll
                        for (int j = 0; j < 4; ++j) pk[j] = (__bf16)(c[j] * scale);
                        *reinterpret_cast<bf16x4*>(smem + QS_OFF + t * 64 +
                            (((ct & 1) * 32 + hi * 8) ^ tsw)) = pk;
                    } else {
                        bf16x4 pk;
#pragma unroll
                        for (int j = 0; j < 4; ++j) pk[j] = (__bf16)c[j];
                        *reinterpret_cast<bf16x4*>(smem + KS_OFF + t * 64 +
                            (((ct & 1) * 32 + hi * 8) ^ tsw)) = pk;
                    }
                } else {
                    // V tiles NON-swapped: D[token][d] = mfma(X-frag, W-frag)
                    // -> c[j] = V[token = wrow+rb*16+hi*4+j][d = (ct&1)*16+lr]
                    // -> 4 consecutive tokens at one VT row: packed 8B store
#pragma unroll
                    for (int kc = 0; kc < 4; ++kc) {
                        const bf16x8 wf = *reinterpret_cast<const bf16x8*>(wp + kc * 32 + hi * 8);
                        c = __builtin_amdgcn_mfma_f32_16x16x32_bf16(Xf[rb][kc], wf, c, 0, 0, 0);
                    }
                    const int d  = (ct & 1) * 16 + lr;
                    const int t0 = wrow + rb * 16 + hi * 4;
                    bf16x4 pk;
#pragma unroll
                    for (int j = 0; j < 4; ++j) pk[j] = (__bf16)c[j];
                    *reinterpret_cast<bf16x4*>(smem + VT_OFF + d * 512 +
                        ((t0 * 2) ^ ((d & 7) << 4))) = pk;
                }
            }
        }
        __syncthreads();

        // ---- attention, fused S->exp2->PV per 32-token k-chunk ----
#pragma unroll
        for (int rb = 0; rb < 2; ++rb) {
            const int rt = wave * 2 + rb;               // q-token tile index
            const int tq = wrow + rb * 16 + lr;
            const bf16x8 qf = *reinterpret_cast<const bf16x8*>(
                smem + QS_OFF + tq * 64 + ((hi * 16) ^ (((tq >> 1) & 3) << 4)));
            char* pb = smem + PB_OFF + wave * 1024;
            const int psw = ((lr >> 1) & 3) << 4;
            const float* bT = biasT + ((size_t)((h * 16) * 16 + rt) * 64 + lane) * 4;

            float lsum = 0.f;
            f32x4 O0 = (f32x4){0.f, 0.f, 0.f, 0.f};
            f32x4 O1 = (f32x4){0.f, 0.f, 0.f, 0.f};
#pragma unroll 2
            for (int kcc = 0; kcc < 8; ++kcc) {
#pragma unroll
                for (int tt = 0; tt < 2; ++tt) {
                    const int ct = kcc * 2 + tt;
                    const int tk = ct * 16 + lr;
                    const bf16x8 kf = *reinterpret_cast<const bf16x8*>(
                        smem + KS_OFF + tk * 64 + ((hi * 16) ^ (((tk >> 1) & 3) << 4)));
                    // bias rides in as the MFMA C-operand (pre-scaled by log2e)
                    const f32x4 bv = *reinterpret_cast<const f32x4*>(bT + ct * 4096);
                    f32x4 s = __builtin_amdgcn_mfma_f32_16x16x32_bf16(kf, qf, bv, 0, 0, 0);
                    // s[j] = log2e * (S + bias)[k = ct*16+hi*4+j][q = rt*16+lr]
                    bf16x4 pk;
#pragma unroll
                    for (int j = 0; j < 4; ++j) {
                        const float p = __builtin_amdgcn_exp2f(s[j]);  // raw v_exp_f32
                        lsum += p;
                        pk[j] = (__bf16)p;
                    }
                    *reinterpret_cast<bf16x4*>(pb + lr * 64 + ((tt * 32 + hi * 8) ^ psw)) = pk;
                }
                const bf16x8 pf = *reinterpret_cast<const bf16x8*>(
                    pb + lr * 64 + ((hi * 16) ^ psw));
                const bf16x8 v0 = *reinterpret_cast<const bf16x8*>(
                    smem + VT_OFF + lr * 512 + ((kcc * 64 + hi * 16) ^ ((lr & 7) << 4)));
                const bf16x8 v1 = *reinterpret_cast<const bf16x8*>(
                    smem + VT_OFF + (16 + lr) * 512 + ((kcc * 64 + hi * 16) ^ ((lr & 7) << 4)));
                O0 = __builtin_amdgcn_mfma_f32_16x16x32_bf16(v0, pf, O0, 0, 0, 0);
                O1 = __builtin_amdgcn_mfma_f32_16x16x32_bf16(v1, pf, O1, 0, 0, 0);
            }
            lsum += __shfl_xor(lsum, 16, 64);
            lsum += __shfl_xor(lsum, 32, 64);
            const float rl = 1.f / lsum;

            // pack O^T halves into one bf16x8 -> single 16B store
            // memory position p = hi*8+e holds d = (e<4)? hi*4+e : 16+hi*4+(e-4)
            bf16x8 ov;
#pragma unroll
            for (int j = 0; j < 4; ++j) {
                ov[j]     = (__bf16)(O0[j] * rl);
                ov[j + 4] = (__bf16)(O1[j] * rl);
            }
            const size_t rp = ((size_t)b * NTOK + tq) * DIM + h * 32;
            *reinterpret_cast<bf16x8*>(O_ws + rp + hi * 8) = ov;
        }
    }
}

// ---------------- proj GEMM kernel: out = O @ Wp + b ----------------
// (k-axis permutation is baked into projT; reads are position-space)
__global__ __launch_bounds__(256) void proj_kernel(
    const __bf16* __restrict__ O_ws, const __bf16* __restrict__ projT,
    const float* __restrict__ proj_b, float* __restrict__ out)
{
    const int tid = threadIdx.x;
    const int wave = tid >> 6, lane = tid & 63;
    const int lr = lane & 15, hi = lane >> 4;
    const int row0 = blockIdx.x * 128 + wave * 32;

#pragma unroll
    for (int rb = 0; rb < 2; ++rb) {
        const size_t t = (size_t)row0 + rb * 16 + lr;
        bf16x8 af[4];
#pragma unroll
        for (int kc = 0; kc < 4; ++kc)
            af[kc] = *reinterpret_cast<const bf16x8*>(O_ws + t * DIM + kc * 32 + hi * 8);
#pragma unroll
        for (int ct = 0; ct < 8; ++ct) {
            f32x4 a = (f32x4){0.f, 0.f, 0.f, 0.f};
#pragma unroll
            for (int kc = 0; kc < 4; ++kc) {
                const bf16x8 wpf = *reinterpret_cast<const bf16x8*>(
                    projT + (ct * 16 + lr) * 128 + kc * 32 + hi * 8);
                a = __builtin_amdgcn_mfma_f32_16x16x32_bf16(wpf, af[kc], a, 0, 0, 0);
            }
            const float4 pbv = *reinterpret_cast<const float4*>(proj_b + ct * 16 + hi * 4);
            f32x4 st;
            st[0] = a[0] + pbv.x; st[1] = a[1] + pbv.y;
            st[2] = a[2] + pbv.z; st[3] = a[3] + pbv.w;
            *reinterpret_cast<f32x4*>(out + t * DIM + ct * 16 + hi * 4) = st;
        }
    }
}

// ---------------- launcher ----------------

extern "C" void kernel_launch(void* const* d_in, const int* in_sizes, int n_in,
                              void* d_out, int out_size, void* d_ws, size_t ws_size,
                              hipStream_t stream)
{
    const float* x          = (const float*)d_in[0];
    const float* noise      = (const float*)d_in[1];
    const float* qkv_w      = (const float*)d_in[2];
    const float* proj_w     = (const float*)d_in[3];
    const float* proj_b     = (const float*)d_in[4];
    const float* bias_table = (const float*)d_in[5];
    const float* nstr       = (const float*)d_in[6];
    float* out = (float*)d_out;
    (void)in_sizes; (void)n_in; (void)out_size; (void)ws_size;

    char* ws = (char*)d_ws;
    const size_t OFF_BIAS  = 0;                                   // 1 MiB
    const size_t OFF_QKVT  = (size_t)1 << 20;                     // 96 KiB
    const size_t OFF_PROJT = OFF_QKVT + 384 * 128 * 2;            // 32 KiB
    const size_t OFF_O     = (size_t)2 << 20;                     // 64 MiB

    float*  biasT = (float*)(ws + OFF_BIAS);
    __bf16* qkvT  = (__bf16*)(ws + OFF_QKVT);
    __bf16* projT = (__bf16*)(ws + OFF_PROJT);
    __bf16* O_ws  = (__bf16*)(ws + OFF_O);

    prep_kernel<<<512, 256, 0, stream>>>(bias_table, qkv_w, proj_w, biasT, qkvT, projT);

    hipFuncSetAttribute(reinterpret_cast<const void*>(attn_main),
                        hipFuncAttributeMaxDynamicSharedMemorySize, SMEM_BYTES);
    attn_main<<<1024, 512, SMEM_BYTES, stream>>>(x, noise, nstr, biasT, qkvT, O_ws);
    proj_kernel<<<2048, 256, 0, stream>>>(O_ws, projT, proj_b, out);
}

// Round 9
// 250.618 us; speedup vs baseline: 1.5663x; 1.0278x over previous
//
#include <hip/hip_runtime.h>

typedef __bf16 bf16x8 __attribute__((ext_vector_type(8)));
typedef __bf16 bf16x4 __attribute__((ext_vector_type(4)));
typedef float  f32x4  __attribute__((ext_vector_type(4)));

#define NTOK 256
#define DIM  128

// LDS layout (48 KiB -> 2 blocks/CU):
//  QS [256 tok][32 d] bf16, row 64B, swizzle: 16B-slot ^= ((t>>1)&3)<<4   : 16384
//  KS same as QS                                                          : 16384
//  VT [32 d][256 pos] bf16, row 512B, swizzle: byte ^= ((d&7)<<4)         : 16384
//     V is stored in PV-contraction POSITION SPACE: within 32-token chunk
//     w, position p = hi*8 + tt*4 + j holds token 32w + tt*16 + hi*4 + j.
//     This makes the S C-fragment concat(pk_tt0, pk_tt1) directly usable
//     as the PV B-operand -> NO P staging in LDS at all.
#define QS_OFF 0
#define KS_OFF 16384
#define VT_OFF 32768
#define SMEM_BYTES 49152

#define LOG2E 1.4426950408889634f

// ---------------- prep kernel (tiny, run once per launch) ----------------
// g in [0,65536):        biasT fragment table (pre-scaled by log2e)
// g in [65536,131072):   qkvT / projT bf16 transposed weights
//
// biasT_frag[((h*16+kt)*16+qt)*64+lane][j] =
//     log2e * bias[h][q=qt*16+(lane&15)][k=kt*16+(lane>>4)*4+j]
//
// projT k-axis is PERMUTED to match the attn O-store order: within head,
// memory position p = hi*8+e holds d = (e<4) ? hi*4+e : 16+hi*4+(e-4).
__global__ void prep_kernel(const float* __restrict__ bias_table,
                            const float* __restrict__ qkv_w,
                            const float* __restrict__ proj_w,
                            float* __restrict__ biasT,
                            __bf16* __restrict__ qkvT,
                            __bf16* __restrict__ projT)
{
    const int g = blockIdx.x * 256 + threadIdx.x;       // 0..131071
    if (g < 65536) {
        const int lane = g & 63;
        const int tile = g >> 6;                        // ((h*16+kt)*16+qt)
        const int qt = tile & 15, kt = (tile >> 4) & 15, h = tile >> 8;
        const int lr = lane & 15, rg = lane >> 4;
        // idx(q,k) = (rq-rk+15)*31 + (cq-ck+15);  rq=qt, cq=lr, rk=kt, ck=rg*4+j
        const int base = (qt - kt + 15) * 31 + (lr - rg * 4 + 15);
        float4 v;
        v.x = bias_table[(base - 0) * 4 + h] * LOG2E;
        v.y = bias_table[(base - 1) * 4 + h] * LOG2E;
        v.z = bias_table[(base - 2) * 4 + h] * LOG2E;
        v.w = bias_table[(base - 3) * 4 + h] * LOG2E;
        *reinterpret_cast<float4*>(biasT + (size_t)g * 4) = v;
    } else {
        const int g1 = g - 65536;
        if (g1 < 49152) {
            const int k = g1 / 384, colg = g1 - k * 384;
            qkvT[colg * 128 + k] = (__bf16)qkv_w[g1];
        } else {
            const int g2 = g1 - 49152;
            const int k = g2 >> 7, col = g2 & 127;      // k = source proj_w row
            const int h = k >> 5, d = k & 31;
            const int p = ((d & 15) >> 2) * 8 + ((d >> 4) & 1) * 4 + (d & 3);
            projT[col * 128 + h * 32 + p] = (__bf16)proj_w[g2];
        }
    }
}

// ---------------- attention kernel (QKV + attn, O^T -> O_ws bf16) ----------------
// R3 shape: 8 waves x 32 token rows, 2 blocks/CU, launch_bounds(512,2).
// Keep arch VGPR <= 64: reported VGPR is arch-only; compiler parks ~64 AGPR
// alongside; total <=128 = the 4-waves/SIMD tier (R4: 68 arch -> 1 block).
// R9 delta: P staging LDS round-trip ELIMINATED — V stored in position
// space, PV B-frag = concat of the two S C-frags, pure-register.

__global__ __launch_bounds__(512, 2) void attn_main(
    const float* __restrict__ x, const float* __restrict__ noise,
    const float* __restrict__ nstr, const float* __restrict__ biasT,
    const __bf16* __restrict__ qkvT, __bf16* __restrict__ O_ws)
{
    extern __shared__ char smem[];
    const int b = blockIdx.x, tid = threadIdx.x;
    const int wave = tid >> 6, lane = tid & 63;
    const int lr = lane & 15, hi = lane >> 4;
    const int wrow = wave * 32;

    const float ns    = nstr[0];
    const float scale = 0.17677669529663689f * LOG2E;   // 32^-0.5 * log2e, folded into Q

    // X fragments in regs (noise added, bf16). Lane (lr,hi) holds X[token=
    // wrow+rb*16+lr][k=kc*32+hi*8+e] — valid as BOTH A-frag (row=token) and
    // B-frag (col=token): A/B lane-data layouts coincide.
    bf16x8 Xf[2][4];
#pragma unroll
    for (int rb = 0; rb < 2; ++rb) {
        const int row = wrow + rb * 16 + lr;
        const float nz = noise[(size_t)b * NTOK + row] * ns;
        const float* prow = x + ((size_t)b * NTOK + row) * DIM;
#pragma unroll
        for (int kc = 0; kc < 4; ++kc) {
            const float4 a0 = *reinterpret_cast<const float4*>(prow + kc * 32 + hi * 8);
            const float4 a1 = *reinterpret_cast<const float4*>(prow + kc * 32 + hi * 8 + 4);
            bf16x8 v;
            v[0] = (__bf16)(a0.x + nz); v[1] = (__bf16)(a0.y + nz);
            v[2] = (__bf16)(a0.z + nz); v[3] = (__bf16)(a0.w + nz);
            v[4] = (__bf16)(a1.x + nz); v[5] = (__bf16)(a1.y + nz);
            v[6] = (__bf16)(a1.z + nz); v[7] = (__bf16)(a1.w + nz);
            Xf[rb][kc] = v;
        }
    }

#pragma unroll 1
    for (int h = 0; h < 4; ++h) {
        __syncthreads();   // QS/KS/VT rewrite vs previous head's readers
        // ---- QKV GEMM ----
#pragma unroll
        for (int rb = 0; rb < 2; ++rb) {
            const int t = wrow + rb * 16 + lr;          // token in this lane's column
            const int tsw = ((t >> 1) & 3) << 4;
#pragma unroll
            for (int ct = 0; ct < 6; ++ct) {
                const int sec = ct >> 1;
                const int colg = sec * 128 + h * 32 + (ct & 1) * 16 + lr;
                const __bf16* wp = qkvT + colg * 128;
                f32x4 c = (f32x4){0.f, 0.f, 0.f, 0.f};
                if (sec < 2) {
                    // transposed: D[col][token] = mfma(W-frag, X-frag)
#pragma unroll
                    for (int kc = 0; kc < 4; ++kc) {
                        const bf16x8 wf = *reinterpret_cast<const bf16x8*>(wp + kc * 32 + hi * 8);
                        c = __builtin_amdgcn_mfma_f32_16x16x32_bf16(wf, Xf[rb][kc], c, 0, 0, 0);
                    }
                    // c[j] = (dloc = (ct&1)*16 + hi*4 + j, token t)
                    if (sec == 0) {
                        bf16x4 pk;
#pragma unroll
                        for (int j = 0; j < 4; ++j) pk[j] = (__bf16)(c[j] * scale);
                        *reinterpret_cast<bf16x4*>(smem + QS_OFF + t * 64 +
                            (((ct & 1) * 32 + hi * 8) ^ tsw)) = pk;
                    } else {
                        bf16x4 pk;
#pragma unroll
                        for (int j = 0; j < 4; ++j) pk[j] = (__bf16)c[j];
                        *reinterpret_cast<bf16x4*>(smem + KS_OFF + t * 64 +
                            (((ct & 1) * 32 + hi * 8) ^ tsw)) = pk;
                    }
                } else {
                    // V tiles NON-swapped: D[token][d] = mfma(X-frag, W-frag)
                    // -> c[j] = V[token = wrow+rb*16+hi*4+j][d = (ct&1)*16+lr]
                    // POSITION-SPACE store: chunk w=wave, p = hi*8 + rb*4 + j
                    // byte col = wave*64 + hi*16 + rb*8 (+ 2j) -> packed 8B
#pragma unroll
                    for (int kc = 0; kc < 4; ++kc) {
                        const bf16x8 wf = *reinterpret_cast<const bf16x8*>(wp + kc * 32 + hi * 8);
                        c = __builtin_amdgcn_mfma_f32_16x16x32_bf16(Xf[rb][kc], wf, c, 0, 0, 0);
                    }
                    const int d = (ct & 1) * 16 + lr;
                    bf16x4 pk;
#pragma unroll
                    for (int j = 0; j < 4; ++j) pk[j] = (__bf16)c[j];
                    *reinterpret_cast<bf16x4*>(smem + VT_OFF + d * 512 +
                        ((wave * 64 + hi * 16 + rb * 8) ^ ((d & 7) << 4))) = pk;
                }
            }
        }
        __syncthreads();

        // ---- attention: S->exp2->PV per 32-token k-chunk, P fully in-register ----
#pragma unroll
        for (int rb = 0; rb < 2; ++rb) {
            const int rt = wave * 2 + rb;               // q-token tile index
            const int tq = wrow + rb * 16 + lr;
            const bf16x8 qf = *reinterpret_cast<const bf16x8*>(
                smem + QS_OFF + tq * 64 + ((hi * 16) ^ (((tq >> 1) & 3) << 4)));
            const float* bT = biasT + ((size_t)((h * 16) * 16 + rt) * 64 + lane) * 4;

            float lsum = 0.f;
            f32x4 O0 = (f32x4){0.f, 0.f, 0.f, 0.f};
            f32x4 O1 = (f32x4){0.f, 0.f, 0.f, 0.f};
#pragma unroll 2
            for (int kcc = 0; kcc < 8; ++kcc) {
                const int tk0 = kcc * 32 + lr;
                const int tk1 = tk0 + 16;
                const bf16x8 kf0 = *reinterpret_cast<const bf16x8*>(
                    smem + KS_OFF + tk0 * 64 + ((hi * 16) ^ (((tk0 >> 1) & 3) << 4)));
                const bf16x8 kf1 = *reinterpret_cast<const bf16x8*>(
                    smem + KS_OFF + tk1 * 64 + ((hi * 16) ^ (((tk1 >> 1) & 3) << 4)));
                const f32x4 bv0 = *reinterpret_cast<const f32x4*>(bT + (kcc * 2 + 0) * 4096);
                const f32x4 bv1 = *reinterpret_cast<const f32x4*>(bT + (kcc * 2 + 1) * 4096);
                // bias rides in as the MFMA C-operand (pre-scaled by log2e)
                const f32x4 s0 = __builtin_amdgcn_mfma_f32_16x16x32_bf16(kf0, qf, bv0, 0, 0, 0);
                const f32x4 s1 = __builtin_amdgcn_mfma_f32_16x16x32_bf16(kf1, qf, bv1, 0, 0, 0);
                // s{tt}[j] = log2e*(S+bias)[k = kcc*32+tt*16+hi*4+j][q = rt*16+lr]
                // PV B-frag position p = hi*8+e <-> k = kcc*32+(e>>2)*16+hi*4+(e&3)
                bf16x8 pf;
#pragma unroll
                for (int j = 0; j < 4; ++j) {
                    const float p0 = __builtin_amdgcn_exp2f(s0[j]);  // raw v_exp_f32
                    const float p1 = __builtin_amdgcn_exp2f(s1[j]);
                    lsum += p0;
                    lsum += p1;
                    pf[j]     = (__bf16)p0;
                    pf[j + 4] = (__bf16)p1;
                }
                const bf16x8 v0 = *reinterpret_cast<const bf16x8*>(
                    smem + VT_OFF + lr * 512 + ((kcc * 64 + hi * 16) ^ ((lr & 7) << 4)));
                const bf16x8 v1 = *reinterpret_cast<const bf16x8*>(
                    smem + VT_OFF + (16 + lr) * 512 + ((kcc * 64 + hi * 16) ^ ((lr & 7) << 4)));
                O0 = __builtin_amdgcn_mfma_f32_16x16x32_bf16(v0, pf, O0, 0, 0, 0);
                O1 = __builtin_amdgcn_mfma_f32_16x16x32_bf16(v1, pf, O1, 0, 0, 0);
            }
            lsum += __shfl_xor(lsum, 16, 64);
            lsum += __shfl_xor(lsum, 32, 64);
            const float rl = 1.f / lsum;

            // pack O^T halves into one bf16x8 -> single 16B store
            // memory position p = hi*8+e holds d = (e<4)? hi*4+e : 16+hi*4+(e-4)
            bf16x8 ov;
#pragma unroll
            for (int j = 0; j < 4; ++j) {
                ov[j]     = (__bf16)(O0[j] * rl);
                ov[j + 4] = (__bf16)(O1[j] * rl);
            }
            const size_t rp = ((size_t)b * NTOK + tq) * DIM + h * 32;
            *reinterpret_cast<bf16x8*>(O_ws + rp + hi * 8) = ov;
        }
    }
}

// ---------------- proj GEMM kernel: out = O @ Wp + b ----------------
// (k-axis permutation is baked into projT; reads are position-space)
__global__ __launch_bounds__(256) void proj_kernel(
    const __bf16* __restrict__ O_ws, const __bf16* __restrict__ projT,
    const float* __restrict__ proj_b, float* __restrict__ out)
{
    const int tid = threadIdx.x;
    const int wave = tid >> 6, lane = tid & 63;
    const int lr = lane & 15, hi = lane >> 4;
    const int row0 = blockIdx.x * 128 + wave * 32;

#pragma unroll
    for (int rb = 0; rb < 2; ++rb) {
        const size_t t = (size_t)row0 + rb * 16 + lr;
        bf16x8 af[4];
#pragma unroll
        for (int kc = 0; kc < 4; ++kc)
            af[kc] = *reinterpret_cast<const bf16x8*>(O_ws + t * DIM + kc * 32 + hi * 8);
#pragma unroll
        for (int ct = 0; ct < 8; ++ct) {
            f32x4 a = (f32x4){0.f, 0.f, 0.f, 0.f};
#pragma unroll
            for (int kc = 0; kc < 4; ++kc) {
                const bf16x8 wpf = *reinterpret_cast<const bf16x8*>(
                    projT + (ct * 16 + lr) * 128 + kc * 32 + hi * 8);
                a = __builtin_amdgcn_mfma_f32_16x16x32_bf16(wpf, af[kc], a, 0, 0, 0);
            }
            const float4 pbv = *reinterpret_cast<const float4*>(proj_b + ct * 16 + hi * 4);
            f32x4 st;
            st[0] = a[0] + pbv.x; st[1] = a[1] + pbv.y;
            st[2] = a[2] + pbv.z; st[3] = a[3] + pbv.w;
            *reinterpret_cast<f32x4*>(out + t * DIM + ct * 16 + hi * 4) = st;
        }
    }
}

// ---------------- launcher ----------------

extern "C" void kernel_launch(void* const* d_in, const int* in_sizes, int n_in,
                              void* d_out, int out_size, void* d_ws, size_t ws_size,
                              hipStream_t stream)
{
    const float* x          = (const float*)d_in[0];
    const float* noise      = (const float*)d_in[1];
    const float* qkv_w      = (const float*)d_in[2];
    const float* proj_w     = (const float*)d_in[3];
    const float* proj_b     = (const float*)d_in[4];
    const float* bias_table = (const float*)d_in[5];
    const float* nstr       = (const float*)d_in[6];
    float* out = (float*)d_out;
    (void)in_sizes; (void)n_in; (void)out_size; (void)ws_size;

    char* ws = (char*)d_ws;
    const size_t OFF_BIAS  = 0;                                   // 1 MiB
    const size_t OFF_QKVT  = (size_t)1 << 20;                     // 96 KiB
    const size_t OFF_PROJT = OFF_QKVT + 384 * 128 * 2;            // 32 KiB
    const size_t OFF_O     = (size_t)2 << 20;                     // 64 MiB

    float*  biasT = (float*)(ws + OFF_BIAS);
    __bf16* qkvT  = (__bf16*)(ws + OFF_QKVT);
    __bf16* projT = (__bf16*)(ws + OFF_PROJT);
    __bf16* O_ws  = (__bf16*)(ws + OFF_O);

    prep_kernel<<<512, 256, 0, stream>>>(bias_table, qkv_w, proj_w, biasT, qkvT, projT);

    hipFuncSetAttribute(reinterpret_cast<const void*>(attn_main),
                        hipFuncAttributeMaxDynamicSharedMemorySize, SMEM_BYTES);
    attn_main<<<1024, 512, SMEM_BYTES, stream>>>(x, noise, nstr, biasT, qkvT, O_ws);
    proj_kernel<<<2048, 256, 0, stream>>>(O_ws, projT, proj_b, out);
}

// Round 10
// 199.390 us; speedup vs baseline: 1.9688x; 1.2569x over previous
//
#include <hip/hip_runtime.h>

typedef __bf16 bf16x8 __attribute__((ext_vector_type(8)));
typedef __bf16 bf16x4 __attribute__((ext_vector_type(4)));
typedef float  f32x4  __attribute__((ext_vector_type(4)));

#define NTOK 256
#define DIM  128

// LDS layout (72 KiB -> 2 blocks/CU = 144K <= 160K):
//  QS [256 tok][32 d] bf16, row 64B, swizzle: 16B-slot ^= ((t>>1)&3)<<4   : 16384
//  KS same as QS                                                          : 16384
//  VT [32 d][256 pos] bf16, row 512B, swizzle: byte ^= ((d&7)<<4)         : 16384
//     (V in PV-contraction position space; PV B-frag built in-register)
//  WS [96 col][256B]  per-head qkv weight slice, slot-swizzled            : 24576
//     staged via global_load_lds from the pre-permuted qkvS table;
//     linear dst + pre-swizzled source + swizzled read (rule #21)
#define QS_OFF 0
#define KS_OFF 16384
#define VT_OFF 32768
#define WS_OFF 49152
#define SMEM_BYTES 73728

#define LOG2E 1.4426950408889634f

// ---------------- prep kernel (tiny, run once per launch) ----------------
// g in [0,65536):           biasT fragment table (pre-scaled by log2e)
// g1 = g-65536 in [0,49152): qkvS staged-weight image (bf16, permuted+swizzled)
// remaining 16384:          projT (k-permuted to match attn O-store order)
//
// biasT_frag[((h*16+kt)*16+qt)*64+lane][j] =
//     log2e * bias[h][q=qt*16+(lane&15)][k=kt*16+(lane>>4)*4+j]
//
// qkvS per head = 24576 bytes; byte L holds WS image content:
//   i = L>>8 (weight row 0..95), p = (L>>4)&15 (physical 16B slot), b=(L&15)>>1
//   k    = ((p ^ (i&15))<<3) + b
//   colg = (i>>5)*128 + h*32 + (i&31)          // Q cols | K cols | V cols
//   value = qkv_w[k][colg]
// so an attn read of k-slot s at physical slot s^(i&15) yields k = s*8..s*8+7.
__global__ void prep_kernel(const float* __restrict__ bias_table,
                            const float* __restrict__ qkv_w,
                            const float* __restrict__ proj_w,
                            float* __restrict__ biasT,
                            __bf16* __restrict__ qkvS,
                            __bf16* __restrict__ projT)
{
    const int g = blockIdx.x * 256 + threadIdx.x;       // 0..131071
    if (g < 65536) {
        const int lane = g & 63;
        const int tile = g >> 6;                        // ((h*16+kt)*16+qt)
        const int qt = tile & 15, kt = (tile >> 4) & 15, h = tile >> 8;
        const int lr = lane & 15, rg = lane >> 4;
        // idx(q,k) = (rq-rk+15)*31 + (cq-ck+15);  rq=qt, cq=lr, rk=kt, ck=rg*4+j
        const int base = (qt - kt + 15) * 31 + (lr - rg * 4 + 15);
        float4 v;
        v.x = bias_table[(base - 0) * 4 + h] * LOG2E;
        v.y = bias_table[(base - 1) * 4 + h] * LOG2E;
        v.z = bias_table[(base - 2) * 4 + h] * LOG2E;
        v.w = bias_table[(base - 3) * 4 + h] * LOG2E;
        *reinterpret_cast<float4*>(biasT + (size_t)g * 4) = v;
    } else {
        const int g1 = g - 65536;
        if (g1 < 49152) {
            const int h = g1 / 12288, r = g1 - h * 12288;   // r = bf16 elem in head image
            const int i = r >> 7;                           // weight row 0..95
            const int p = (r >> 3) & 15;                    // physical 16B slot
            const int bb = r & 7;
            const int k = ((p ^ (i & 15)) << 3) + bb;
            const int colg = ((i >> 5) << 7) + (h << 5) + (i & 31);
            qkvS[g1] = (__bf16)qkv_w[k * 384 + colg];
        } else {
            const int g2 = g1 - 49152;
            const int k = g2 >> 7, col = g2 & 127;      // k = source proj_w row
            const int h = k >> 5, d = k & 31;
            const int p = ((d & 15) >> 2) * 8 + ((d >> 4) & 1) * 4 + (d & 3);
            projT[col * 128 + h * 32 + p] = (__bf16)proj_w[g2];
        }
    }
}

// ---------------- attention kernel (QKV + attn, O^T -> O_ws bf16) ----------------
// R3 shape: 8 waves x 32 token rows, 2 blocks/CU, launch_bounds(512,2).
// Keep arch VGPR <= 64 (total arch+acc <= 128 = 4-waves/SIMD tier; R4 evidence).
// R10 delta: per-head weight slice staged into LDS (WS) via async
// global_load_lds issued during the PREVIOUS head's attention phase (T14);
// QKV wf reads become conflict-free ds_read_b128; ct-outer loop reuses wf
// across both rb (24 reads/wave-head instead of 48 global loads).

__global__ __launch_bounds__(512, 2) void attn_main(
    const float* __restrict__ x, const float* __restrict__ noise,
    const float* __restrict__ nstr, const float* __restrict__ biasT,
    const __bf16* __restrict__ qkvS, __bf16* __restrict__ O_ws)
{
    extern __shared__ char smem[];
    const int b = blockIdx.x, tid = threadIdx.x;
    const int wave = tid >> 6, lane = tid & 63;
    const int lr = lane & 15, hi = lane >> 4;
    const int wrow = wave * 32;

    const float ns    = nstr[0];
    const float scale = 0.17677669529663689f * LOG2E;   // 32^-0.5 * log2e, folded into Q

    // async stage of head hh's weight image into WS: linear LDS dst
    // (wave-uniform base; HW adds lane*16), per-lane global src.
    auto stage_w = [&](int hh) {
#pragma unroll
        for (int is = 0; is < 3; ++is) {
            const __bf16* gsrc = qkvS + hh * 12288 + ((is * 8192 + tid * 16) >> 1);
            char* dst = smem + WS_OFF + is * 8192 + wave * 1024;
            __builtin_amdgcn_global_load_lds(
                (const __attribute__((address_space(1))) void*)(size_t)gsrc,
                (__attribute__((address_space(3))) void*)(unsigned)(size_t)dst,
                16, 0, 0);
        }
    };

    // X fragments in regs (noise added, bf16). Lane (lr,hi) holds X[token=
    // wrow+rb*16+lr][k=kc*32+hi*8+e] — valid as BOTH A-frag (row=token) and
    // B-frag (col=token): A/B lane-data layouts coincide.
    bf16x8 Xf[2][4];
#pragma unroll
    for (int rb = 0; rb < 2; ++rb) {
        const int row = wrow + rb * 16 + lr;
        const float nz = noise[(size_t)b * NTOK + row] * ns;
        const float* prow = x + ((size_t)b * NTOK + row) * DIM;
#pragma unroll
        for (int kc = 0; kc < 4; ++kc) {
            const float4 a0 = *reinterpret_cast<const float4*>(prow + kc * 32 + hi * 8);
            const float4 a1 = *reinterpret_cast<const float4*>(prow + kc * 32 + hi * 8 + 4);
            bf16x8 v;
            v[0] = (__bf16)(a0.x + nz); v[1] = (__bf16)(a0.y + nz);
            v[2] = (__bf16)(a0.z + nz); v[3] = (__bf16)(a0.w + nz);
            v[4] = (__bf16)(a1.x + nz); v[5] = (__bf16)(a1.y + nz);
            v[6] = (__bf16)(a1.z + nz); v[7] = (__bf16)(a1.w + nz);
            Xf[rb][kc] = v;
        }
    }

    stage_w(0);   // head 0 weights; drained by the first __syncthreads

#pragma unroll 1
    for (int h = 0; h < 4; ++h) {
        __syncthreads();   // A: staging complete (implicit vmcnt(0) drain);
                           //    QS/KS/VT rewrite safe vs prev head's readers
        // ---- QKV GEMM: wf from WS (ds_read_b128), reused across both rb ----
#pragma unroll
        for (int ct = 0; ct < 6; ++ct) {
            const int sec = ct >> 1;
            const int i = ct * 16 + lr;                 // weight row; i&15 == lr
            bf16x8 wf[4];
#pragma unroll
            for (int kc = 0; kc < 4; ++kc)
                wf[kc] = *reinterpret_cast<const bf16x8*>(
                    smem + WS_OFF + i * 256 + ((((kc << 2) + hi) ^ lr) << 4));
#pragma unroll
            for (int rb = 0; rb < 2; ++rb) {
                f32x4 c = (f32x4){0.f, 0.f, 0.f, 0.f};
                if (sec < 2) {
                    // transposed: D[col][token] = mfma(W-frag, X-frag)
#pragma unroll
                    for (int kc = 0; kc < 4; ++kc)
                        c = __builtin_amdgcn_mfma_f32_16x16x32_bf16(wf[kc], Xf[rb][kc], c, 0, 0, 0);
                    const int t = wrow + rb * 16 + lr;
                    const int tsw = ((t >> 1) & 3) << 4;
                    bf16x4 pk;
                    if (sec == 0) {
#pragma unroll
                        for (int j = 0; j < 4; ++j) pk[j] = (__bf16)(c[j] * scale);
                        *reinterpret_cast<bf16x4*>(smem + QS_OFF + t * 64 +
                            (((ct & 1) * 32 + hi * 8) ^ tsw)) = pk;
                    } else {
#pragma unroll
                        for (int j = 0; j < 4; ++j) pk[j] = (__bf16)c[j];
                        *reinterpret_cast<bf16x4*>(smem + KS_OFF + t * 64 +
                            (((ct & 1) * 32 + hi * 8) ^ tsw)) = pk;
                    }
                } else {
                    // V NON-swapped: D[token][d] = mfma(X-frag, W-frag)
                    // c[j] = V[token = wrow+rb*16+hi*4+j][d = (ct&1)*16+lr]
                    // position-space packed 8B store (chunk=wave, p=hi*8+rb*4+j)
#pragma unroll
                    for (int kc = 0; kc < 4; ++kc)
                        c = __builtin_amdgcn_mfma_f32_16x16x32_bf16(Xf[rb][kc], wf[kc], c, 0, 0, 0);
                    const int d = (ct & 1) * 16 + lr;
                    bf16x4 pk;
#pragma unroll
                    for (int j = 0; j < 4; ++j) pk[j] = (__bf16)c[j];
                    *reinterpret_cast<bf16x4*>(smem + VT_OFF + d * 512 +
                        ((wave * 64 + hi * 16 + rb * 8) ^ ((d & 7) << 4))) = pk;
                }
            }
        }
        __syncthreads();   // B: Q/K/V ready; WS reads done -> safe to restage

        if (h < 3) stage_w(h + 1);   // async prefetch under the attention phase

        // ---- attention: S->exp2->PV per 32-token k-chunk, P fully in-register ----
#pragma unroll
        for (int rb = 0; rb < 2; ++rb) {
            const int rt = wave * 2 + rb;               // q-token tile index
            const int tq = wrow + rb * 16 + lr;
            const bf16x8 qf = *reinterpret_cast<const bf16x8*>(
                smem + QS_OFF + tq * 64 + ((hi * 16) ^ (((tq >> 1) & 3) << 4)));
            const float* bT = biasT + ((size_t)((h * 16) * 16 + rt) * 64 + lane) * 4;

            float lsum = 0.f;
            f32x4 O0 = (f32x4){0.f, 0.f, 0.f, 0.f};
            f32x4 O1 = (f32x4){0.f, 0.f, 0.f, 0.f};
#pragma unroll 2
            for (int kcc = 0; kcc < 8; ++kcc) {
                const int tk0 = kcc * 32 + lr;
                const int tk1 = tk0 + 16;
                const bf16x8 kf0 = *reinterpret_cast<const bf16x8*>(
                    smem + KS_OFF + tk0 * 64 + ((hi * 16) ^ (((tk0 >> 1) & 3) << 4)));
                const bf16x8 kf1 = *reinterpret_cast<const bf16x8*>(
                    smem + KS_OFF + tk1 * 64 + ((hi * 16) ^ (((tk1 >> 1) & 3) << 4)));
                const f32x4 bv0 = *reinterpret_cast<const f32x4*>(bT + (kcc * 2 + 0) * 4096);
                const f32x4 bv1 = *reinterpret_cast<const f32x4*>(bT + (kcc * 2 + 1) * 4096);
                // bias rides in as the MFMA C-operand (pre-scaled by log2e)
                const f32x4 s0 = __builtin_amdgcn_mfma_f32_16x16x32_bf16(kf0, qf, bv0, 0, 0, 0);
                const f32x4 s1 = __builtin_amdgcn_mfma_f32_16x16x32_bf16(kf1, qf, bv1, 0, 0, 0);
                // s{tt}[j] = log2e*(S+bias)[k = kcc*32+tt*16+hi*4+j][q = rt*16+lr]
                // PV B-frag position p = hi*8+e <-> k = kcc*32+(e>>2)*16+hi*4+(e&3)
                bf16x8 pf;
#pragma unroll
                for (int j = 0; j < 4; ++j) {
                    const float p0 = __builtin_amdgcn_exp2f(s0[j]);  // raw v_exp_f32
                    const float p1 = __builtin_amdgcn_exp2f(s1[j]);
                    lsum += p0;
                    lsum += p1;
                    pf[j]     = (__bf16)p0;
                    pf[j + 4] = (__bf16)p1;
                }
                const bf16x8 v0 = *reinterpret_cast<const bf16x8*>(
                    smem + VT_OFF + lr * 512 + ((kcc * 64 + hi * 16) ^ ((lr & 7) << 4)));
                const bf16x8 v1 = *reinterpret_cast<const bf16x8*>(
                    smem + VT_OFF + (16 + lr) * 512 + ((kcc * 64 + hi * 16) ^ ((lr & 7) << 4)));
                O0 = __builtin_amdgcn_mfma_f32_16x16x32_bf16(v0, pf, O0, 0, 0, 0);
                O1 = __builtin_amdgcn_mfma_f32_16x16x32_bf16(v1, pf, O1, 0, 0, 0);
            }
            lsum += __shfl_xor(lsum, 16, 64);
            lsum += __shfl_xor(lsum, 32, 64);
            const float rl = 1.f / lsum;

            // pack O^T halves into one bf16x8 -> single 16B store
            // memory position p = hi*8+e holds d = (e<4)? hi*4+e : 16+hi*4+(e-4)
            bf16x8 ov;
#pragma unroll
            for (int j = 0; j < 4; ++j) {
                ov[j]     = (__bf16)(O0[j] * rl);
                ov[j + 4] = (__bf16)(O1[j] * rl);
            }
            const size_t rp = ((size_t)b * NTOK + tq) * DIM + h * 32;
            *reinterpret_cast<bf16x8*>(O_ws + rp + hi * 8) = ov;
        }
    }
}

// ---------------- proj GEMM kernel: out = O @ Wp + b ----------------
// (k-axis permutation is baked into projT; reads are position-space)
__global__ __launch_bounds__(256) void proj_kernel(
    const __bf16* __restrict__ O_ws, const __bf16* __restrict__ projT,
    const float* __restrict__ proj_b, float* __restrict__ out)
{
    const int tid = threadIdx.x;
    const int wave = tid >> 6, lane = tid & 63;
    const int lr = lane & 15, hi = lane >> 4;
    const int row0 = blockIdx.x * 128 + wave * 32;

#pragma unroll
    for (int rb = 0; rb < 2; ++rb) {
        const size_t t = (size_t)row0 + rb * 16 + lr;
        bf16x8 af[4];
#pragma unroll
        for (int kc = 0; kc < 4; ++kc)
            af[kc] = *reinterpret_cast<const bf16x8*>(O_ws + t * DIM + kc * 32 + hi * 8);
#pragma unroll
        for (int ct = 0; ct < 8; ++ct) {
            f32x4 a = (f32x4){0.f, 0.f, 0.f, 0.f};
#pragma unroll
            for (int kc = 0; kc < 4; ++kc) {
                const bf16x8 wpf = *reinterpret_cast<const bf16x8*>(
                    projT + (ct * 16 + lr) * 128 + kc * 32 + hi * 8);
                a = __builtin_amdgcn_mfma_f32_16x16x32_bf16(wpf, af[kc], a, 0, 0, 0);
            }
            const float4 pbv = *reinterpret_cast<const float4*>(proj_b + ct * 16 + hi * 4);
            f32x4 st;
            st[0] = a[0] + pbv.x; st[1] = a[1] + pbv.y;
            st[2] = a[2] + pbv.z; st[3] = a[3] + pbv.w;
            *reinterpret_cast<f32x4*>(out + t * DIM + ct * 16 + hi * 4) = st;
        }
    }
}

// ---------------- launcher ----------------

extern "C" void kernel_launch(void* const* d_in, const int* in_sizes, int n_in,
                              void* d_out, int out_size, void* d_ws, size_t ws_size,
                              hipStream_t stream)
{
    const float* x          = (const float*)d_in[0];
    const float* noise      = (const float*)d_in[1];
    const float* qkv_w      = (const float*)d_in[2];
    const float* proj_w     = (const float*)d_in[3];
    const float* proj_b     = (const float*)d_in[4];
    const float* bias_table = (const float*)d_in[5];
    const float* nstr       = (const float*)d_in[6];
    float* out = (float*)d_out;
    (void)in_sizes; (void)n_in; (void)out_size; (void)ws_size;

    char* ws = (char*)d_ws;
    const size_t OFF_BIAS  = 0;                                   // 1 MiB
    const size_t OFF_QKVS  = (size_t)1 << 20;                     // 96 KiB
    const size_t OFF_PROJT = OFF_QKVS + 49152 * 2;                // 32 KiB
    const size_t OFF_O     = (size_t)2 << 20;                     // 64 MiB

    float*  biasT = (float*)(ws + OFF_BIAS);
    __bf16* qkvS  = (__bf16*)(ws + OFF_QKVS);
    __bf16* projT = (__bf16*)(ws + OFF_PROJT);
    __bf16* O_ws  = (__bf16*)(ws + OFF_O);

    prep_kernel<<<512, 256, 0, stream>>>(bias_table, qkv_w, proj_w, biasT, qkvS, projT);

    hipFuncSetAttribute(reinterpret_cast<const void*>(attn_main),
                        hipFuncAttributeMaxDynamicSharedMemorySize, SMEM_BYTES);
    attn_main<<<1024, 512, SMEM_BYTES, stream>>>(x, noise, nstr, biasT, qkvS, O_ws);
    proj_kernel<<<2048, 256, 0, stream>>>(O_ws, projT, proj_b, out);
}

// Round 11
// 171.272 us; speedup vs baseline: 2.2920x; 1.1642x over previous
//
#include <hip/hip_runtime.h>

typedef __bf16 bf16x8 __attribute__((ext_vector_type(8)));
typedef __bf16 bf16x4 __attribute__((ext_vector_type(4)));
typedef float  f32x4  __attribute__((ext_vector_type(4)));

#define NTOK 256
#define DIM  128

// LDS layout (72 KiB -> 2 blocks/CU = 144K <= 160K):
//  QS [256 tok][32 d] bf16, row 64B, swizzle: 16B-slot ^= ((t>>1)&3)<<4   : 16384
//  KS same as QS                                                          : 16384
//  VT [32 d][256 pos] bf16, row 512B, swizzle: byte ^= ((d&7)<<4)         : 16384
//     (V in PV-contraction position space; PV B-frag built in-register)
//  WS [96 col][256B]  per-head qkv weight slice, slot-swizzled            : 24576
//     staged via global_load_lds from the pre-permuted qkvS table;
//     linear dst + pre-swizzled source + swizzled read (rule #21)
#define QS_OFF 0
#define KS_OFF 16384
#define VT_OFF 32768
#define WS_OFF 49152
#define SMEM_BYTES 73728

#define LOG2E 1.4426950408889634f

// ---------------- prep kernel (tiny, run once per launch) ----------------
// g in [0,65536):            biasT fragment table (pre-scaled by log2e)
// g1 = g-65536 in [0,49152): qkvS staged-weight image (bf16, permuted+swizzled)
// remaining 16384:           projT (k-permuted to match attn O-store order)
//
// biasT_frag[((h*16+kt)*16+qt)*64+lane][j] =
//     log2e * bias[h][q=qt*16+(lane&15)][k=kt*16+(lane>>4)*4+j]
//
// qkvS per head = 24576 bytes; byte L holds WS image content:
//   i = L>>8 (weight row 0..95), p = (L>>4)&15 (physical 16B slot), b=(L&15)>>1
//   k    = ((p ^ (i&15))<<3) + b
//   colg = (i>>5)*128 + h*32 + (i&31)          // Q cols | K cols | V cols
//   value = qkv_w[k][colg]
// so an attn read of k-slot s at physical slot s^(i&15) yields k = s*8..s*8+7.
__global__ void prep_kernel(const float* __restrict__ bias_table,
                            const float* __restrict__ qkv_w,
                            const float* __restrict__ proj_w,
                            float* __restrict__ biasT,
                            __bf16* __restrict__ qkvS,
                            __bf16* __restrict__ projT)
{
    const int g = blockIdx.x * 256 + threadIdx.x;       // 0..131071
    if (g < 65536) {
        const int lane = g & 63;
        const int tile = g >> 6;                        // ((h*16+kt)*16+qt)
        const int qt = tile & 15, kt = (tile >> 4) & 15, h = tile >> 8;
        const int lr = lane & 15, rg = lane >> 4;
        // idx(q,k) = (rq-rk+15)*31 + (cq-ck+15);  rq=qt, cq=lr, rk=kt, ck=rg*4+j
        const int base = (qt - kt + 15) * 31 + (lr - rg * 4 + 15);
        float4 v;
        v.x = bias_table[(base - 0) * 4 + h] * LOG2E;
        v.y = bias_table[(base - 1) * 4 + h] * LOG2E;
        v.z = bias_table[(base - 2) * 4 + h] * LOG2E;
        v.w = bias_table[(base - 3) * 4 + h] * LOG2E;
        *reinterpret_cast<float4*>(biasT + (size_t)g * 4) = v;
    } else {
        const int g1 = g - 65536;
        if (g1 < 49152) {
            const int h = g1 / 12288, r = g1 - h * 12288;   // r = bf16 elem in head image
            const int i = r >> 7;                           // weight row 0..95
            const int p = (r >> 3) & 15;                    // physical 16B slot
            const int bb = r & 7;
            const int k = ((p ^ (i & 15)) << 3) + bb;
            const int colg = ((i >> 5) << 7) + (h << 5) + (i & 31);
            qkvS[g1] = (__bf16)qkv_w[k * 384 + colg];
        } else {
            const int g2 = g1 - 49152;
            const int k = g2 >> 7, col = g2 & 127;      // k = source proj_w row
            const int h = k >> 5, d = k & 31;
            const int p = ((d & 15) >> 2) * 8 + ((d >> 4) & 1) * 4 + (d & 3);
            projT[col * 128 + h * 32 + p] = (__bf16)proj_w[g2];
        }
    }
}

// ---------------- fused kernel: QKV + attn + proj epilogue ----------------
// R3 shape: 8 waves x 32 token rows, 2 blocks/CU, launch_bounds(512,2).
// Keep arch VGPR <= 64 (total arch+acc <= 128 = 4-waves/SIMD tier; R4 evidence).
// R11 delta: proj fused as an epilogue — the wave reads back ITS OWN O rows
// from O_ws (written seconds^H^Hmicroseconds ago -> L2-hot) after a vmcnt
// drain, and does the 128x128 proj GEMM + bias + f32 out stores in-kernel.
// Block n's memory-heavy epilogue overlaps block n+1's compute (2 blocks/CU).

__global__ __launch_bounds__(512, 2) void attn_main(
    const float* __restrict__ x, const float* __restrict__ noise,
    const float* __restrict__ nstr, const float* __restrict__ biasT,
    const __bf16* __restrict__ qkvS, const __bf16* __restrict__ projT,
    const float* __restrict__ proj_b, __bf16* __restrict__ O_ws,
    float* __restrict__ out)
{
    extern __shared__ char smem[];
    const int b = blockIdx.x, tid = threadIdx.x;
    const int wave = tid >> 6, lane = tid & 63;
    const int lr = lane & 15, hi = lane >> 4;
    const int wrow = wave * 32;

    const float ns    = nstr[0];
    const float scale = 0.17677669529663689f * LOG2E;   // 32^-0.5 * log2e, folded into Q

    // async stage of head hh's weight image into WS: linear LDS dst
    // (wave-uniform base; HW adds lane*16), per-lane global src.
    auto stage_w = [&](int hh) {
#pragma unroll
        for (int is = 0; is < 3; ++is) {
            const __bf16* gsrc = qkvS + hh * 12288 + ((is * 8192 + tid * 16) >> 1);
            char* dst = smem + WS_OFF + is * 8192 + wave * 1024;
            __builtin_amdgcn_global_load_lds(
                (const __attribute__((address_space(1))) void*)(size_t)gsrc,
                (__attribute__((address_space(3))) void*)(unsigned)(size_t)dst,
                16, 0, 0);
        }
    };

    // X fragments in regs (noise added, bf16). Lane (lr,hi) holds X[token=
    // wrow+rb*16+lr][k=kc*32+hi*8+e] — valid as BOTH A-frag (row=token) and
    // B-frag (col=token): A/B lane-data layouts coincide.
    bf16x8 Xf[2][4];
#pragma unroll
    for (int rb = 0; rb < 2; ++rb) {
        const int row = wrow + rb * 16 + lr;
        const float nz = noise[(size_t)b * NTOK + row] * ns;
        const float* prow = x + ((size_t)b * NTOK + row) * DIM;
#pragma unroll
        for (int kc = 0; kc < 4; ++kc) {
            const float4 a0 = *reinterpret_cast<const float4*>(prow + kc * 32 + hi * 8);
            const float4 a1 = *reinterpret_cast<const float4*>(prow + kc * 32 + hi * 8 + 4);
            bf16x8 v;
            v[0] = (__bf16)(a0.x + nz); v[1] = (__bf16)(a0.y + nz);
            v[2] = (__bf16)(a0.z + nz); v[3] = (__bf16)(a0.w + nz);
            v[4] = (__bf16)(a1.x + nz); v[5] = (__bf16)(a1.y + nz);
            v[6] = (__bf16)(a1.z + nz); v[7] = (__bf16)(a1.w + nz);
            Xf[rb][kc] = v;
        }
    }

    stage_w(0);   // head 0 weights; drained by the first __syncthreads

#pragma unroll 1
    for (int h = 0; h < 4; ++h) {
        __syncthreads();   // A: staging complete (implicit vmcnt(0) drain);
                           //    QS/KS/VT rewrite safe vs prev head's readers
        // ---- QKV GEMM: wf from WS (ds_read_b128), reused across both rb ----
#pragma unroll
        for (int ct = 0; ct < 6; ++ct) {
            const int sec = ct >> 1;
            const int i = ct * 16 + lr;                 // weight row; i&15 == lr
            bf16x8 wf[4];
#pragma unroll
            for (int kc = 0; kc < 4; ++kc)
                wf[kc] = *reinterpret_cast<const bf16x8*>(
                    smem + WS_OFF + i * 256 + ((((kc << 2) + hi) ^ lr) << 4));
#pragma unroll
            for (int rb = 0; rb < 2; ++rb) {
                f32x4 c = (f32x4){0.f, 0.f, 0.f, 0.f};
                if (sec < 2) {
                    // transposed: D[col][token] = mfma(W-frag, X-frag)
#pragma unroll
                    for (int kc = 0; kc < 4; ++kc)
                        c = __builtin_amdgcn_mfma_f32_16x16x32_bf16(wf[kc], Xf[rb][kc], c, 0, 0, 0);
                    const int t = wrow + rb * 16 + lr;
                    const int tsw = ((t >> 1) & 3) << 4;
                    bf16x4 pk;
                    if (sec == 0) {
#pragma unroll
                        for (int j = 0; j < 4; ++j) pk[j] = (__bf16)(c[j] * scale);
                        *reinterpret_cast<bf16x4*>(smem + QS_OFF + t * 64 +
                            (((ct & 1) * 32 + hi * 8) ^ tsw)) = pk;
                    } else {
#pragma unroll
                        for (int j = 0; j < 4; ++j) pk[j] = (__bf16)c[j];
                        *reinterpret_cast<bf16x4*>(smem + KS_OFF + t * 64 +
                            (((ct & 1) * 32 + hi * 8) ^ tsw)) = pk;
                    }
                } else {
                    // V NON-swapped: D[token][d] = mfma(X-frag, W-frag)
                    // c[j] = V[token = wrow+rb*16+hi*4+j][d = (ct&1)*16+lr]
                    // position-space packed 8B store (chunk=wave, p=hi*8+rb*4+j)
#pragma unroll
                    for (int kc = 0; kc < 4; ++kc)
                        c = __builtin_amdgcn_mfma_f32_16x16x32_bf16(Xf[rb][kc], wf[kc], c, 0, 0, 0);
                    const int d = (ct & 1) * 16 + lr;
                    bf16x4 pk;
#pragma unroll
                    for (int j = 0; j < 4; ++j) pk[j] = (__bf16)c[j];
                    *reinterpret_cast<bf16x4*>(smem + VT_OFF + d * 512 +
                        ((wave * 64 + hi * 16 + rb * 8) ^ ((d & 7) << 4))) = pk;
                }
            }
        }
        __syncthreads();   // B: Q/K/V ready; WS reads done -> safe to restage

        if (h < 3) stage_w(h + 1);   // async prefetch under the attention phase

        // ---- attention: S->exp2->PV per 32-token k-chunk, P fully in-register ----
#pragma unroll
        for (int rb = 0; rb < 2; ++rb) {
            const int rt = wave * 2 + rb;               // q-token tile index
            const int tq = wrow + rb * 16 + lr;
            const bf16x8 qf = *reinterpret_cast<const bf16x8*>(
                smem + QS_OFF + tq * 64 + ((hi * 16) ^ (((tq >> 1) & 3) << 4)));
            const float* bT = biasT + ((size_t)((h * 16) * 16 + rt) * 64 + lane) * 4;

            float lsum = 0.f;
            f32x4 O0 = (f32x4){0.f, 0.f, 0.f, 0.f};
            f32x4 O1 = (f32x4){0.f, 0.f, 0.f, 0.f};
#pragma unroll 2
            for (int kcc = 0; kcc < 8; ++kcc) {
                const int tk0 = kcc * 32 + lr;
                const int tk1 = tk0 + 16;
                const bf16x8 kf0 = *reinterpret_cast<const bf16x8*>(
                    smem + KS_OFF + tk0 * 64 + ((hi * 16) ^ (((tk0 >> 1) & 3) << 4)));
                const bf16x8 kf1 = *reinterpret_cast<const bf16x8*>(
                    smem + KS_OFF + tk1 * 64 + ((hi * 16) ^ (((tk1 >> 1) & 3) << 4)));
                const f32x4 bv0 = *reinterpret_cast<const f32x4*>(bT + (kcc * 2 + 0) * 4096);
                const f32x4 bv1 = *reinterpret_cast<const f32x4*>(bT + (kcc * 2 + 1) * 4096);
                // bias rides in as the MFMA C-operand (pre-scaled by log2e)
                const f32x4 s0 = __builtin_amdgcn_mfma_f32_16x16x32_bf16(kf0, qf, bv0, 0, 0, 0);
                const f32x4 s1 = __builtin_amdgcn_mfma_f32_16x16x32_bf16(kf1, qf, bv1, 0, 0, 0);
                // s{tt}[j] = log2e*(S+bias)[k = kcc*32+tt*16+hi*4+j][q = rt*16+lr]
                // PV B-frag position p = hi*8+e <-> k = kcc*32+(e>>2)*16+hi*4+(e&3)
                bf16x8 pf;
#pragma unroll
                for (int j = 0; j < 4; ++j) {
                    const float p0 = __builtin_amdgcn_exp2f(s0[j]);  // raw v_exp_f32
                    const float p1 = __builtin_amdgcn_exp2f(s1[j]);
                    lsum += p0;
                    lsum += p1;
                    pf[j]     = (__bf16)p0;
                    pf[j + 4] = (__bf16)p1;
                }
                const bf16x8 v0 = *reinterpret_cast<const bf16x8*>(
                    smem + VT_OFF + lr * 512 + ((kcc * 64 + hi * 16) ^ ((lr & 7) << 4)));
                const bf16x8 v1 = *reinterpret_cast<const bf16x8*>(
                    smem + VT_OFF + (16 + lr) * 512 + ((kcc * 64 + hi * 16) ^ ((lr & 7) << 4)));
                O0 = __builtin_amdgcn_mfma_f32_16x16x32_bf16(v0, pf, O0, 0, 0, 0);
                O1 = __builtin_amdgcn_mfma_f32_16x16x32_bf16(v1, pf, O1, 0, 0, 0);
            }
            lsum += __shfl_xor(lsum, 16, 64);
            lsum += __shfl_xor(lsum, 32, 64);
            const float rl = 1.f / lsum;

            // pack O^T halves into one bf16x8 -> single 16B store
            // memory position p = hi*8+e holds d = (e<4)? hi*4+e : 16+hi*4+(e-4)
            bf16x8 ov;
#pragma unroll
            for (int j = 0; j < 4; ++j) {
                ov[j]     = (__bf16)(O0[j] * rl);
                ov[j + 4] = (__bf16)(O1[j] * rl);
            }
            const size_t rp = ((size_t)b * NTOK + tq) * DIM + h * 32;
            *reinterpret_cast<bf16x8*>(O_ws + rp + hi * 8) = ov;
        }
    }

    // ---- fused proj epilogue: out[t] = O[t] @ Wp + b ----
    // The wave reads back ITS OWN O rows (all 4 heads) — written above, so
    // L2-hot. Fragment layouts coincide: af[kc=h] == that head's ov on this
    // lane. Drain stores first (same-wave store->load visibility).
    asm volatile("s_waitcnt vmcnt(0)" ::: "memory");
#pragma unroll
    for (int rb = 0; rb < 2; ++rb) {
        const size_t t = (size_t)b * NTOK + wrow + rb * 16 + lr;
        bf16x8 af[4];
#pragma unroll
        for (int kc = 0; kc < 4; ++kc)
            af[kc] = *reinterpret_cast<const bf16x8*>(O_ws + t * DIM + kc * 32 + hi * 8);
#pragma unroll
        for (int ct = 0; ct < 8; ++ct) {
            f32x4 a = (f32x4){0.f, 0.f, 0.f, 0.f};
#pragma unroll
            for (int kc = 0; kc < 4; ++kc) {
                const bf16x8 wpf = *reinterpret_cast<const bf16x8*>(
                    projT + (ct * 16 + lr) * 128 + kc * 32 + hi * 8);
                a = __builtin_amdgcn_mfma_f32_16x16x32_bf16(wpf, af[kc], a, 0, 0, 0);
            }
            const float4 pbv = *reinterpret_cast<const float4*>(proj_b + ct * 16 + hi * 4);
            f32x4 st;
            st[0] = a[0] + pbv.x; st[1] = a[1] + pbv.y;
            st[2] = a[2] + pbv.z; st[3] = a[3] + pbv.w;
            *reinterpret_cast<f32x4*>(out + t * DIM + ct * 16 + hi * 4) = st;
        }
    }
}

// ---------------- launcher ----------------

extern "C" void kernel_launch(void* const* d_in, const int* in_sizes, int n_in,
                              void* d_out, int out_size, void* d_ws, size_t ws_size,
                              hipStream_t stream)
{
    const float* x          = (const float*)d_in[0];
    const float* noise      = (const float*)d_in[1];
    const float* qkv_w      = (const float*)d_in[2];
    const float* proj_w     = (const float*)d_in[3];
    const float* proj_b     = (const float*)d_in[4];
    const float* bias_table = (const float*)d_in[5];
    const float* nstr       = (const float*)d_in[6];
    float* out = (float*)d_out;
    (void)in_sizes; (void)n_in; (void)out_size; (void)ws_size;

    char* ws = (char*)d_ws;
    const size_t OFF_BIAS  = 0;                                   // 1 MiB
    const size_t OFF_QKVS  = (size_t)1 << 20;                     // 96 KiB
    const size_t OFF_PROJT = OFF_QKVS + 49152 * 2;                // 32 KiB
    const size_t OFF_O     = (size_t)2 << 20;                     // 64 MiB

    float*  biasT = (float*)(ws + OFF_BIAS);
    __bf16* qkvS  = (__bf16*)(ws + OFF_QKVS);
    __bf16* projT = (__bf16*)(ws + OFF_PROJT);
    __bf16* O_ws  = (__bf16*)(ws + OFF_O);

    prep_kernel<<<512, 256, 0, stream>>>(bias_table, qkv_w, proj_w, biasT, qkvS, projT);

    hipFuncSetAttribute(reinterpret_cast<const void*>(attn_main),
                        hipFuncAttributeMaxDynamicSharedMemorySize, SMEM_BYTES);
    attn_main<<<1024, 512, SMEM_BYTES, stream>>>(
        x, noise, nstr, biasT, qkvS, projT, proj_b, O_ws, out);
}